// Round 7
// baseline (2080.556 us; speedup 1.0000x reference)
//
#include <hip/hip_runtime.h>

#define B_N 32768
#define D_N 512
#define K_N 8192
#define EMA 0.99f
#define ONE_M_EMA 0.01f
#define EPS_ 1e-5f
#define CCOST 0.25f

// ws layout (fast path):
// [0, 262144)      : u64 packed[B_N] (low32 = idx)
// [262144, 294912) : float wsq[K_N]
// [294912, 294932) : scal[5]: loss_sum, n_sum, maxwl2, maxw2, qcount
// zp[16][32768][32] bf16-hi, swizzled        @ ZP_OFF   (33.55 MB)
// wp[16][8192][32]                           @ WP_OFF   ( 8.39 MB)
// dist12[B][32 tile][4 wn] float4{v1,i1,v2,_}@ DIST_OFF (67.11 MB)
// thresh[B] f32 @ THR_OFF; zh2/zl2[B] @ ZH2/ZL2; qrows[B] @ QROWS
// AUX (aliases zp, used only after score): cnt/offs/cursor/rowlist/lpart
#define ZP_OFF    295936ull
#define WP_OFF    33850368ull
#define DIST_OFF  42238976ull
#define THR_OFF   109347840ull
#define ZH2_OFF   109478912ull
#define ZL2_OFF   109609984ull
#define QROWS_OFF 109741056ull
#define WS_NEED   109872128ull
#define CNT_OFF    295936ull
#define OFFS_OFF   332800ull
#define CURS_OFF   365568ull
#define ROWL_OFF   398336ull
#define LPART_OFF  529408ull

typedef __attribute__((ext_vector_type(8))) short bf16x8;
typedef __attribute__((ext_vector_type(4))) float f32x4;

// ---------------------------------------------------------------- prep ----
__global__ __launch_bounds__(256) void prep_kernel(const float* __restrict__ w,
                                                   const float* __restrict__ ecs,
                                                   float* __restrict__ wsq,
                                                   float* __restrict__ ncs_out) {
  int row  = blockIdx.x * 4 + (threadIdx.x >> 6);
  int lane = threadIdx.x & 63;
  const float* p = w + (size_t)row * D_N + lane * 8;
  float4 a = *(const float4*)p;
  float4 b = *(const float4*)(p + 4);
  float s = a.x*a.x + a.y*a.y + a.z*a.z + a.w*a.w
          + b.x*b.x + b.y*b.y + b.z*b.z + b.w*b.w;
  #pragma unroll
  for (int off = 32; off; off >>= 1) s += __shfl_down(s, off);
  if (lane == 0) wsq[row] = s;

  int gid = blockIdx.x * 256 + threadIdx.x;           // fallback-path ncs init
  if (gid < K_N) ncs_out[gid] = EMA * ecs[gid];
}

__global__ __launch_bounds__(256) void prep_nedw(const float4* __restrict__ edw,
                                                 float4* __restrict__ nedw) {
  int i = blockIdx.x * 256 + threadIdx.x;
  float4 v = edw[i];
  v.x *= EMA; v.y *= EMA; v.z *= EMA; v.w *= EMA;
  nedw[i] = v;
}

// ------------------------------------------------------------ pre-split ---
// hi-only packs + norms. Layout identical to round-6 per slice (chunk-XOR).
__global__ __launch_bounds__(256) void split_z(const float* __restrict__ x,
                                               ushort* __restrict__ xp,
                                               float* __restrict__ zh2,
                                               float* __restrict__ zl2) {
  int g = blockIdx.x * 256 + threadIdx.x;
  int row = g >> 6, c = g & 63;
  const float* src = x + (size_t)row * 512 + c * 8;
  float v[8];
  *(float4*)&v[0] = *(const float4*)&src[0];
  *(float4*)&v[4] = *(const float4*)&src[4];
  uint hw[4]; float h2 = 0.f, l2 = 0.f;
  #pragma unroll
  for (int i = 0; i < 4; i++) {
    uint b0 = __float_as_uint(v[2*i]);
    uint b1 = __float_as_uint(v[2*i+1]);
    float h0 = __uint_as_float(b0 & 0xFFFF0000u);
    float h1 = __uint_as_float(b1 & 0xFFFF0000u);
    float r0 = v[2*i] - h0, r1 = v[2*i+1] - h1;
    hw[i] = (b0 >> 16) | (b1 & 0xFFFF0000u);
    h2 += h0*h0 + h1*h1;  l2 += r0*r0 + r1*r1;
  }
  int si = c >> 2;
  int p  = (c & 3) ^ ((row >> 1) & 3);
  size_t d0 = (size_t)si * (32768u * 32u) + (size_t)row * 32 + (size_t)p * 8;
  *(uint4*)&xp[d0] = (uint4){hw[0], hw[1], hw[2], hw[3]};
  #pragma unroll
  for (int off = 32; off; off >>= 1) { h2 += __shfl_down(h2, off); l2 += __shfl_down(l2, off); }
  if (c == 0) { zh2[row] = h2; zl2[row] = l2; }
}

__global__ __launch_bounds__(256) void split_w(const float* __restrict__ x,
                                               ushort* __restrict__ xp,
                                               unsigned* __restrict__ maxwl2,
                                               unsigned* __restrict__ maxw2) {
  int g = blockIdx.x * 256 + threadIdx.x;
  int row = g >> 6, c = g & 63;
  const float* src = x + (size_t)row * 512 + c * 8;
  float v[8];
  *(float4*)&v[0] = *(const float4*)&src[0];
  *(float4*)&v[4] = *(const float4*)&src[4];
  uint hw[4]; float w2 = 0.f, l2 = 0.f;
  #pragma unroll
  for (int i = 0; i < 4; i++) {
    uint b0 = __float_as_uint(v[2*i]);
    uint b1 = __float_as_uint(v[2*i+1]);
    float h0 = __uint_as_float(b0 & 0xFFFF0000u);
    float h1 = __uint_as_float(b1 & 0xFFFF0000u);
    float r0 = v[2*i] - h0, r1 = v[2*i+1] - h1;
    hw[i] = (b0 >> 16) | (b1 & 0xFFFF0000u);
    w2 += v[2*i]*v[2*i] + v[2*i+1]*v[2*i+1];  l2 += r0*r0 + r1*r1;
  }
  int si = c >> 2;
  int p  = (c & 3) ^ ((row >> 1) & 3);
  size_t d0 = (size_t)si * (8192u * 32u) + (size_t)row * 32 + (size_t)p * 8;
  *(uint4*)&xp[d0] = (uint4){hw[0], hw[1], hw[2], hw[3]};
  #pragma unroll
  for (int off = 32; off; off >>= 1) { w2 += __shfl_down(w2, off); l2 += __shfl_down(l2, off); }
  if (c == 0) {
    atomicMax(maxwl2, __float_as_uint(l2));
    atomicMax(maxw2,  __float_as_uint(w2));
  }
}

// --------------------------------------------------------- score (hi-hi) --
// 256x256 tile, 8 waves (2M x 4N), K'=512 -> 16 slices/col-tile, 128 phases.
// Ring of 4 LDS slots, frag E/O double-buffer, counted vmcnt(8).
constexpr int COLT2 = 8;

#define GLDS(SRC, DST) __builtin_amdgcn_global_load_lds((const unsigned int*)(SRC), (unsigned int*)(DST), 16, 0, 0)

#define PHASE(AC, BC, AL, BL, G)                                               \
  {                                                                            \
    const int g_ = (G);                                                        \
    if (g_ + 1 <= 127) {                                                       \
      const char* Ab_ = (const char*)As[(g_ + 1) & 3] + aoff;                  \
      const char* Bb_ = (const char*)Bs[(g_ + 1) & 3] + boff;                  \
      _Pragma("unroll")                                                        \
      for (int i_ = 0; i_ < 8; i_++) AL[i_] = *(const bf16x8*)(Ab_ + i_ * 1024);\
      _Pragma("unroll")                                                        \
      for (int j_ = 0; j_ < 4; j_++) BL[j_] = *(const bf16x8*)(Bb_ + j_ * 1024);\
    }                                                                          \
    if (g_ + 4 <= 127) {                                                       \
      const int slotF_ = sf & 3;                                               \
      GLDS(zA + (size_t)sf * 2097152,        (char*)As[slotF_] + t * 16);      \
      GLDS(zA + (size_t)sf * 2097152 + 8192, (char*)As[slotF_] + 8192 + t * 16);\
      const size_t wOfs_ = (size_t)sf * 524288 + (size_t)ctf * 16384;          \
      GLDS(wB + wOfs_,        (char*)Bs[slotF_] + t * 16);                     \
      GLDS(wB + wOfs_ + 8192, (char*)Bs[slotF_] + 8192 + t * 16);              \
      sf++; if (sf == 16) { sf = 0; ctf++; }                                   \
    }                                                                          \
    __builtin_amdgcn_s_setprio(1);                                             \
    _Pragma("unroll")                                                          \
    for (int i_ = 0; i_ < 8; i_++)                                             \
      _Pragma("unroll")                                                        \
      for (int j_ = 0; j_ < 4; j_++)                                           \
        acc[i_][j_] = __builtin_amdgcn_mfma_f32_16x16x32_bf16(AC[i_], BC[j_],  \
                                                        acc[i_][j_], 0, 0, 0); \
    __builtin_amdgcn_s_setprio(0);                                             \
    asm volatile("s_waitcnt lgkmcnt(0)" ::: "memory");                         \
    if (g_ <= 123)      { asm volatile("s_waitcnt vmcnt(8)" ::: "memory"); }   \
    else if (g_ == 124) { asm volatile("s_waitcnt vmcnt(4)" ::: "memory"); }   \
    else if (g_ == 125) { asm volatile("s_waitcnt vmcnt(0)" ::: "memory"); }   \
    __builtin_amdgcn_s_barrier();                                              \
    __builtin_amdgcn_sched_barrier(0);                                         \
  }

__global__ __launch_bounds__(512, 2) void score_h(
    const ushort* __restrict__ zp, const ushort* __restrict__ wp,
    const float* __restrict__ wsq, float4* __restrict__ dist12) {
  __shared__ ushort As[4][8192];
  __shared__ ushort Bs[4][8192];
  __shared__ float wsqs[2048];

  const int t = threadIdx.x, lane = t & 63, wid = t >> 6;
  const int wm = wid >> 2, wn = wid & 3;
  const int l15 = lane & 15, lg = (lane >> 4) & 3;
  const int row0 = blockIdx.x * 256;
  const int cg0  = blockIdx.y * 2048;

  const char* zA = (const char*)zp + ((size_t)(row0 + (t >> 2)) * 64 + (size_t)(t & 3) * 16);
  const char* wB = (const char*)wp + ((size_t)(cg0  + (t >> 2)) * 64 + (size_t)(t & 3) * 16);

  const int swz  = (l15 >> 1) & 3;
  const int aoff = (wm * 128 + l15) * 64 + ((lg ^ swz) * 16);
  const int boff = (wn * 64  + l15) * 64 + ((lg ^ swz) * 16);

  { float4 v = *(const float4*)&wsq[cg0 + t * 4]; *(float4*)&wsqs[t * 4] = v; }
  __syncthreads();

  #pragma unroll
  for (int s0 = 0; s0 < 4; s0++) {
    GLDS(zA + (size_t)s0 * 2097152,        (char*)As[s0] + t * 16);
    GLDS(zA + (size_t)s0 * 2097152 + 8192, (char*)As[s0] + 8192 + t * 16);
    GLDS(wB + (size_t)s0 * 524288,         (char*)Bs[s0] + t * 16);
    GLDS(wB + (size_t)s0 * 524288 + 8192,  (char*)Bs[s0] + 8192 + t * 16);
  }
  asm volatile("s_waitcnt vmcnt(8)" ::: "memory");
  __builtin_amdgcn_s_barrier();
  __builtin_amdgcn_sched_barrier(0);

  bf16x8 aE[8], bE[4], aO[8], bO[4];
  #pragma unroll
  for (int i = 0; i < 8; i++) aE[i] = *(const bf16x8*)((const char*)As[0] + aoff + i * 1024);
  #pragma unroll
  for (int j = 0; j < 4; j++) bE[j] = *(const bf16x8*)((const char*)Bs[0] + boff + j * 1024);
  asm volatile("s_waitcnt lgkmcnt(0)" ::: "memory");
  __builtin_amdgcn_s_barrier();
  __builtin_amdgcn_sched_barrier(0);

  int sf = 4, ctf = 0;

  for (int ct = 0; ct < COLT2; ct++) {
    f32x4 acc[8][4];
    #pragma unroll
    for (int i = 0; i < 8; i++)
      #pragma unroll
      for (int j = 0; j < 4; j++) acc[i][j] = (f32x4){0.f, 0.f, 0.f, 0.f};

    for (int s = 0; s < 16; s += 2) {
      const int g = ct * 16 + s;
      PHASE(aE, bE, aO, bO, g)
      PHASE(aO, bO, aE, bE, g + 1)
    }

    // ---- epilogue: per-entry (v1,i1,v2), butterfly, chunked global writes
    const int tileG = blockIdx.y * 8 + ct;
    #pragma unroll
    for (int ch = 0; ch < 4; ch++) {             // entries e = 8*ch .. 8*ch+7
      float v1[8], v2[8]; int i1[8];
      #pragma unroll
      for (int u = 0; u < 8; u++) {
        const int i = 2 * ch + (u >> 2), r = u & 3;
        float b1 = 3.4e38f, b2 = 3.4e38f; int bi = 0x7FFFFFFF;
        #pragma unroll
        for (int j = 0; j < 4; j++) {
          float wq = wsqs[ct * 256 + wn * 64 + j * 16 + l15];
          float d  = wq - 2.0f * acc[i][j][r];
          int cc   = cg0 + ct * 256 + wn * 64 + j * 16 + l15;
          if (d < b1)      { b2 = b1; b1 = d; bi = cc; }
          else if (d < b2) { b2 = d; }
        }
        v1[u] = b1; i1[u] = bi; v2[u] = b2;
      }
      #pragma unroll
      for (int u = 0; u < 8; u++) {
        float a1 = v1[u], a2 = v2[u]; int ai = i1[u];
        #pragma unroll
        for (int m = 1; m < 16; m <<= 1) {
          float o1 = __shfl_xor(a1, m, 64);
          int   oi = __shfl_xor(ai, m, 64);
          float o2 = __shfl_xor(a2, m, 64);
          bool tb = (o1 < a1) || (o1 == a1 && oi < ai);
          float lose = tb ? a1 : o1;
          a2 = fminf(fminf(a2, o2), lose);
          a1 = tb ? o1 : a1; ai = tb ? oi : ai;
        }
        v1[u] = a1; i1[u] = ai; v2[u] = a2;
      }
      const int wbase = (ch & 1) * 8;
      if (l15 >= wbase && l15 < wbase + 8) {
        const int eu = l15 - wbase;
        float f1 = 0.f, f2 = 0.f; int fi = 0;
        #pragma unroll
        for (int u = 0; u < 8; u++) {            // static-index select (rule #20)
          bool p = (u == eu);
          f1 = p ? v1[u] : f1; fi = p ? i1[u] : fi; f2 = p ? v2[u] : f2;
        }
        const int e = 8 * ch + eu;
        const int rowG = row0 + wm * 128 + (e >> 2) * 16 + lg * 4 + (e & 3);
        float4 st; st.x = f1; st.y = __int_as_float(fi); st.z = f2; st.w = 0.f;
        dist12[(size_t)rowG * 128 + tileG * 4 + wn] = st;
      }
    }
  }
}

// --------------------------------------------------- fixup: decide/queue --
__global__ __launch_bounds__(256) void fixup_kernel(
    const float4* __restrict__ dist12, const float* __restrict__ zh2,
    const float* __restrict__ zl2, const float* __restrict__ scal,
    unsigned long long* __restrict__ packed, float* __restrict__ thresh_arr,
    int* __restrict__ qrows, int* __restrict__ qcount) {
  int row  = blockIdx.x * 4 + (threadIdx.x >> 6);
  int lane = threadIdx.x & 63;
  const float4* base = dist12 + (size_t)row * 128;
  float4 ea = base[lane];
  float4 eb = base[lane + 64];
  float v1, v2; int i1;
  {
    bool tb = (eb.x < ea.x) || (eb.x == ea.x && __float_as_int(eb.y) < __float_as_int(ea.y));
    float lose = tb ? ea.x : eb.x;
    v2 = fminf(fminf(ea.z, eb.z), lose);
    v1 = tb ? eb.x : ea.x;
    i1 = __float_as_int(tb ? eb.y : ea.y);
  }
  #pragma unroll
  for (int m = 1; m < 64; m <<= 1) {
    float o1 = __shfl_xor(v1, m, 64);
    int   oi = __shfl_xor(i1, m, 64);
    float o2 = __shfl_xor(v2, m, 64);
    bool tb = (o1 < v1) || (o1 == v1 && oi < i1);
    float lose = tb ? v1 : o1;
    v2 = fminf(fminf(v2, o2), lose);
    v1 = tb ? o1 : v1; i1 = tb ? oi : i1;
  }
  if (lane == 0) {
    // |dhat - D| <= B = 2(||zh|| ||wl|| + ||zl|| ||w||); candidates within 2B.
    float B = 2.0f * (sqrtf(zh2[row]) * sqrtf(scal[2]) + sqrtf(zl2[row]) * sqrtf(scal[3]));
    float thr = v1 + 2.05f * B + 1e-5f;
    if (v2 > thr) {
      packed[row] = (unsigned long long)(unsigned)i1;
    } else {
      thresh_arr[row] = thr;
      int p = atomicAdd(qcount, 1);
      qrows[p] = row;
    }
  }
}

// ------------------------------------------------ refine: exact f32 dots --
__device__ __forceinline__ float exact_dist(const float* __restrict__ w,
                                            const float* __restrict__ wsq,
                                            float4 za, float4 zb, int ki, int lane) {
  const float* wr = w + (size_t)ki * 512 + lane * 8;
  float4 wa = *(const float4*)wr;
  float4 wb = *(const float4*)(wr + 4);
  float s = za.x*wa.x + za.y*wa.y + za.z*wa.z + za.w*wa.w
          + zb.x*wb.x + zb.y*wb.y + zb.z*wb.z + zb.w*wb.w;
  #pragma unroll
  for (int m = 1; m < 64; m <<= 1) s += __shfl_xor(s, m, 64);
  return wsq[ki] - 2.0f * s;
}

__global__ __launch_bounds__(256) void refine_kernel(
    const float* __restrict__ z, const float* __restrict__ w,
    const float* __restrict__ wsq, const float4* __restrict__ dist12,
    const float* __restrict__ thresh_arr, const int* __restrict__ qrows,
    const int* __restrict__ qcount, unsigned long long* __restrict__ packed) {
  int wgid = (blockIdx.x * 256 + threadIdx.x) >> 6;
  int lane = threadIdx.x & 63;
  int n  = qcount[0];
  int nw = gridDim.x * 4;
  for (int it = wgid; it < n; it += nw) {
    int row = qrows[it];
    float thr = thresh_arr[row];
    const float* zr = z + (size_t)row * 512 + lane * 8;
    float4 za = *(const float4*)zr;
    float4 zb = *(const float4*)(zr + 4);
    const float4* base = dist12 + (size_t)row * 128;
    float bestd = 3.4e38f; int besti = 0x7FFFFFFF;
    #pragma unroll
    for (int half = 0; half < 2; half++) {
      float4 e = base[lane + half * 64];
      unsigned long long mc = __ballot(e.x <= thr);
      unsigned long long ms = __ballot(e.z <= thr);
      while (mc) {                               // single candidates
        int src = __ffsll(mc) - 1; mc &= mc - 1;
        int ki = __shfl(__float_as_int(e.y), src);
        float d = exact_dist(w, wsq, za, zb, ki, lane);
        if (d < bestd || (d == bestd && ki < besti)) { bestd = d; besti = ki; }
      }
      while (ms) {                               // rare: >=2 cands in a granule
        int src = __ffsll(ms) - 1; ms &= ms - 1;
        int g2 = src + half * 64;
        int col0 = (g2 >> 2) * 256 + (g2 & 3) * 64;
        for (int q = 0; q < 64; q++) {
          int ki = col0 + q;
          float d = exact_dist(w, wsq, za, zb, ki, lane);
          if (d < bestd || (d == bestd && ki < besti)) { bestd = d; besti = ki; }
        }
      }
    }
    if (lane == 0) packed[row] = (unsigned long long)(unsigned)besti;
  }
}

// ---------------------------------------- fallback score (round-2 kernel) --
constexpr int LDP = 40;
constexpr int KSPLIT = 8, COLT = K_N / KSPLIT / 128;
__device__ __forceinline__ void stage16(const float* __restrict__ g,
                                        ushort* __restrict__ h,
                                        ushort* __restrict__ l) {
  float v[16];
  *(float4*)&v[0]  = *(const float4*)&g[0];
  *(float4*)&v[4]  = *(const float4*)&g[4];
  *(float4*)&v[8]  = *(const float4*)&g[8];
  *(float4*)&v[12] = *(const float4*)&g[12];
  uint hw[8], lw[8];
  #pragma unroll
  for (int i = 0; i < 8; i++) {
    uint b0 = __float_as_uint(v[2*i]);
    uint b1 = __float_as_uint(v[2*i+1]);
    float r0 = v[2*i]   - __uint_as_float(b0 & 0xFFFF0000u);
    float r1 = v[2*i+1] - __uint_as_float(b1 & 0xFFFF0000u);
    hw[i] = (b0 >> 16) | (b1 & 0xFFFF0000u);
    lw[i] = (__float_as_uint(r0) >> 16) | (__float_as_uint(r1) & 0xFFFF0000u);
  }
  ((uint4*)h)[0] = *(uint4*)&hw[0];
  ((uint4*)h)[1] = *(uint4*)&hw[4];
  ((uint4*)l)[0] = *(uint4*)&lw[0];
  ((uint4*)l)[1] = *(uint4*)&lw[4];
}

__global__ __launch_bounds__(256, 2) void score_argmin_mfma(
    const float* __restrict__ z, const float* __restrict__ w,
    const float* __restrict__ wsq, unsigned long long* __restrict__ packed) {
  __shared__ ushort Ah[128][LDP];
  __shared__ ushort Al[128][LDP];
  __shared__ ushort Bh[128][LDP];
  __shared__ ushort Bl[128][LDP];
  const int t = threadIdx.x, lane = t & 63, wid = t >> 6;
  const int wm = wid >> 1, wn = wid & 1;
  const int l15 = lane & 15, lg = lane >> 4;
  const int row0 = blockIdx.x * 128;
  const int ks0  = blockIdx.y * (K_N / KSPLIT);
  const int srow = t >> 1, skq = (t & 1) * 16;
  float rmin[16]; int ridx[16];
  #pragma unroll
  for (int e = 0; e < 16; e++) { rmin[e] = 3.4e38f; ridx[e] = 0; }
  for (int ct = 0; ct < COLT; ct++) {
    const int c0 = ks0 + ct * 128;
    f32x4 acc[4][4];
    #pragma unroll
    for (int i = 0; i < 4; i++)
      #pragma unroll
      for (int j = 0; j < 4; j++) acc[i][j] = (f32x4){0.f, 0.f, 0.f, 0.f};
    for (int k0 = 0; k0 < D_N; k0 += 32) {
      __syncthreads();
      stage16(&z[(size_t)(row0 + srow) * D_N + k0 + skq], &Ah[srow][skq], &Al[srow][skq]);
      stage16(&w[(size_t)(c0   + srow) * D_N + k0 + skq], &Bh[srow][skq], &Bl[srow][skq]);
      __syncthreads();
      bf16x8 ah[4], al[4], bh[4], bl[4];
      #pragma unroll
      for (int i = 0; i < 4; i++) {
        ah[i] = *(const bf16x8*)&Ah[wm*64 + i*16 + l15][lg*8];
        al[i] = *(const bf16x8*)&Al[wm*64 + i*16 + l15][lg*8];
        bh[i] = *(const bf16x8*)&Bh[wn*64 + i*16 + l15][lg*8];
        bl[i] = *(const bf16x8*)&Bl[wn*64 + i*16 + l15][lg*8];
      }
      #pragma unroll
      for (int i = 0; i < 4; i++)
        #pragma unroll
        for (int j = 0; j < 4; j++) {
          acc[i][j] = __builtin_amdgcn_mfma_f32_16x16x32_bf16(ah[i], bh[j], acc[i][j], 0, 0, 0);
          acc[i][j] = __builtin_amdgcn_mfma_f32_16x16x32_bf16(ah[i], bl[j], acc[i][j], 0, 0, 0);
          acc[i][j] = __builtin_amdgcn_mfma_f32_16x16x32_bf16(al[i], bh[j], acc[i][j], 0, 0, 0);
        }
    }
    float wq[4];
    #pragma unroll
    for (int j = 0; j < 4; j++) wq[j] = wsq[c0 + wn*64 + j*16 + l15];
    #pragma unroll
    for (int i = 0; i < 4; i++)
      #pragma unroll
      for (int r = 0; r < 4; r++) {
        const int e = i * 4 + r;
        #pragma unroll
        for (int j = 0; j < 4; j++) {
          float dist = wq[j] - 2.0f * acc[i][j][r];
          if (dist < rmin[e]) { rmin[e] = dist; ridx[e] = c0 + wn*64 + j*16 + l15; }
        }
      }
  }
  #pragma unroll
  for (int e = 0; e < 16; e++) {
    float v = rmin[e]; int ix = ridx[e];
    #pragma unroll
    for (int m = 1; m < 16; m <<= 1) {
      float ov = __shfl_xor(v, m, 64);
      int   oi = __shfl_xor(ix, m, 64);
      if (ov < v || (ov == v && oi < ix)) { v = ov; ix = oi; }
    }
    rmin[e] = v; ridx[e] = ix;
  }
  const int s = l15;
  float bv = 0.f; int bi = 0;
  #pragma unroll
  for (int e = 0; e < 16; e++) {
    bool p = (e == s);
    bv = p ? rmin[e] : bv;
    bi = p ? ridx[e] : bi;
  }
  unsigned u = __float_as_uint(bv);
  u = (u & 0x80000000u) ? ~u : (u | 0x80000000u);
  unsigned long long key = ((unsigned long long)u << 32) | (unsigned)bi;
  atomicMin(&packed[row0 + wm*64 + (s >> 2)*16 + lg*4 + (s & 3)], key);
}

// ------------------------------------------- counting-sort segment-sum ----
__global__ __launch_bounds__(256) void count_kernel(
    const unsigned long long* __restrict__ packed, int* __restrict__ cnt,
    float* __restrict__ idxout) {
  int row = blockIdx.x * 256 + threadIdx.x;
  int idx = (int)(packed[row] & 0xFFFFFFFFull);
  idxout[row] = (float)idx;
  atomicAdd(&cnt[idx], 1);
}

__global__ __launch_bounds__(256) void scan_kernel(const int* __restrict__ cnt,
                                                   int* __restrict__ offs,
                                                   int* __restrict__ cursor) {
  int t = threadIdx.x;
  int base = t * 32;
  int local[32];
  int s = 0;
  #pragma unroll
  for (int i = 0; i < 32; i++) { local[i] = s; s += cnt[base + i]; }
  __shared__ int ps[257];
  ps[t + 1] = s;
  if (t == 0) ps[0] = 0;
  __syncthreads();
  if (t == 0) { for (int i = 1; i <= 256; i++) ps[i] += ps[i - 1]; }
  __syncthreads();
  int e = ps[t];
  #pragma unroll
  for (int i = 0; i < 32; i++) {
    int o = e + local[i];
    offs[base + i] = o; cursor[base + i] = o;
  }
  if (t == 255) offs[8192] = ps[256];
}

__global__ __launch_bounds__(256) void scatter_ids(
    const unsigned long long* __restrict__ packed, int* __restrict__ cursor,
    int* __restrict__ rowlist) {
  int row = blockIdx.x * 256 + threadIdx.x;
  int idx = (int)(packed[row] & 0xFFFFFFFFull);
  int pos = atomicAdd(&cursor[idx], 1);
  rowlist[pos] = row;
}

__global__ __launch_bounds__(256) void seg_accum(
    const float* __restrict__ z, const float* __restrict__ edw,
    const float* __restrict__ ecs, const int* __restrict__ offs,
    const int* __restrict__ rowlist, float* __restrict__ nedw_out,
    float* __restrict__ ncs_out) {
  int k = blockIdx.x, t = threadIdx.x;
  int s0 = offs[k], s1 = offs[k + 1];
  float ax = 0.f, ay = 0.f;
  for (int r = s0; r < s1; r++) {
    int row = rowlist[r];
    float2 zv = *(const float2*)&z[(size_t)row * D_N + t * 2];
    ax += zv.x; ay += zv.y;
  }
  float2 ev = *(const float2*)&edw[(size_t)k * D_N + t * 2];
  float2 o;
  o.x = EMA * ev.x + ONE_M_EMA * ax;
  o.y = EMA * ev.y + ONE_M_EMA * ay;
  *(float2*)&nedw_out[(size_t)k * D_N + t * 2] = o;
  if (t == 0) ncs_out[k] = EMA * ecs[k] + ONE_M_EMA * (float)(s1 - s0);
}

// ------------------------------------------------ quantize + loss partial --
__global__ __launch_bounds__(256) void quant_loss(
    const float* __restrict__ z, const float* __restrict__ w,
    const unsigned long long* __restrict__ packed,
    float* __restrict__ qout, float* __restrict__ lpart) {
  int row = blockIdx.x, t = threadIdx.x;
  int idx = (int)(packed[row] & 0xFFFFFFFFull);
  float2 zv = *(const float2*)&z[(size_t)row * D_N + t * 2];
  float2 wv = *(const float2*)&w[(size_t)idx * D_N + t * 2];
  float2 q;
  q.x = zv.x + (wv.x - zv.x);
  q.y = zv.y + (wv.y - zv.y);
  *(float2*)&qout[(size_t)row * D_N + t * 2] = q;
  float dx = zv.x - wv.x, dy = zv.y - wv.y;
  float s = dx * dx + dy * dy;
  #pragma unroll
  for (int off = 32; off; off >>= 1) s += __shfl_down(s, off);
  __shared__ float part[4];
  if ((t & 63) == 0) part[t >> 6] = s;
  __syncthreads();
  if (t == 0) lpart[row] = part[0] + part[1] + part[2] + part[3];
}

// ------------------------------------------------------------- reductions -
__global__ __launch_bounds__(256) void reduce2(const float* __restrict__ ncs_out,
                                               const float* __restrict__ lpart,
                                               float* __restrict__ nsum,
                                               float* __restrict__ loss_sum) {
  int t = threadIdx.x;
  float s1 = 0.f, s2 = 0.f;
  for (int i = t; i < K_N; i += 256) s1 += ncs_out[i];
  for (int i = t; i < B_N; i += 256) s2 += lpart[i];
  #pragma unroll
  for (int off = 32; off; off >>= 1) {
    s1 += __shfl_down(s1, off);
    s2 += __shfl_down(s2, off);
  }
  __shared__ float p1[4], p2[4];
  if ((t & 63) == 0) { p1[t >> 6] = s1; p2[t >> 6] = s2; }
  __syncthreads();
  if (t == 0) {
    nsum[0]     = p1[0] + p1[1] + p1[2] + p1[3];
    loss_sum[0] = p2[0] + p2[1] + p2[2] + p2[3];
  }
}

// fallback-path kernels
__global__ __launch_bounds__(256) void gather_scatter(
    const float* __restrict__ z, const float* __restrict__ w,
    const unsigned long long* __restrict__ packed,
    float* __restrict__ qout, float* __restrict__ idxout,
    float* __restrict__ ncs_out, float* __restrict__ nedw_out,
    float* __restrict__ loss_sum) {
  int row = blockIdx.x;
  int t   = threadIdx.x;
  int idx = (int)(packed[row] & 0xFFFFFFFFull);
  float2 zv = *(const float2*)&z[(size_t)row * D_N + t * 2];
  float2 wv = *(const float2*)&w[(size_t)idx * D_N + t * 2];
  float2 q;
  q.x = zv.x + (wv.x - zv.x);
  q.y = zv.y + (wv.y - zv.y);
  *(float2*)&qout[(size_t)row * D_N + t * 2] = q;
  float dx = zv.x - wv.x, dy = zv.y - wv.y;
  float s = dx*dx + dy*dy;
  #pragma unroll
  for (int off = 32; off; off >>= 1) s += __shfl_down(s, off);
  __shared__ float part[4];
  if ((t & 63) == 0) part[t >> 6] = s;
  __syncthreads();
  if (t == 0) {
    atomicAdd(loss_sum, part[0] + part[1] + part[2] + part[3]);
    atomicAdd(&ncs_out[idx], ONE_M_EMA);
    idxout[row] = (float)idx;
  }
  atomicAdd(&nedw_out[(size_t)idx * D_N + t*2],     ONE_M_EMA * zv.x);
  atomicAdd(&nedw_out[(size_t)idx * D_N + t*2 + 1], ONE_M_EMA * zv.y);
}

__global__ __launch_bounds__(256) void reduce_n(const float* __restrict__ ncs_out,
                                                float* __restrict__ nsum) {
  int t = threadIdx.x;
  float s = 0.f;
  for (int i = t; i < K_N; i += 256) s += ncs_out[i];
  #pragma unroll
  for (int off = 32; off; off >>= 1) s += __shfl_down(s, off);
  __shared__ float part[4];
  if ((t & 63) == 0) part[t >> 6] = s;
  __syncthreads();
  if (t == 0) nsum[0] = part[0] + part[1] + part[2] + part[3];
}

__global__ __launch_bounds__(256) void finalize(
    const float* __restrict__ ncs_out, const float* __restrict__ nedw_out,
    float* __restrict__ nw_out, const float* __restrict__ nsum,
    const float* __restrict__ loss_sum, float* __restrict__ loss_out) {
  size_t i = (size_t)blockIdx.x * 256 + threadIdx.x;
  float n = nsum[0];
  int k = (int)(i >> 9);
  float nv = ncs_out[k];
  float cs = (nv + EPS_) / (n + K_N * EPS_) * n;
  nw_out[i] = nedw_out[i] / cs;
  if (i == 0) loss_out[0] = CCOST * loss_sum[0] / (float)((size_t)B_N * D_N);
}

// ------------------------------------------------------------------ launch -
extern "C" void kernel_launch(void* const* d_in, const int* in_sizes, int n_in,
                              void* d_out, int out_size, void* d_ws, size_t ws_size,
                              hipStream_t stream) {
  const float* z   = (const float*)d_in[0];
  const float* w   = (const float*)d_in[1];
  const float* ecs = (const float*)d_in[2];
  const float* edw = (const float*)d_in[3];

  float* out      = (float*)d_out;
  float* qout     = out;
  float* idxout   = out + (size_t)B_N * D_N;
  float* loss_out = idxout + B_N;
  float* nw_out   = loss_out + 1;
  float* ncs_out  = nw_out + (size_t)K_N * D_N;
  float* nedw_out = ncs_out + K_N;

  unsigned long long* packed = (unsigned long long*)d_ws;
  float* wsq      = (float*)((char*)d_ws + 262144);
  float* scal     = (float*)((char*)d_ws + 294912);  // loss,n,maxwl2,maxw2,qcount
  float* loss_sum = scal;
  float* nsum     = scal + 1;

  hipMemsetAsync(d_ws, 0xFF, 262144, stream);
  hipMemsetAsync((void*)scal, 0, 20, stream);

  prep_kernel<<<2048, 256, 0, stream>>>(w, ecs, wsq, ncs_out);

  if (ws_size >= WS_NEED) {
    ushort* zp   = (ushort*)((char*)d_ws + ZP_OFF);
    ushort* wp   = (ushort*)((char*)d_ws + WP_OFF);
    float4* d12  = (float4*)((char*)d_ws + DIST_OFF);
    float* thra  = (float*)((char*)d_ws + THR_OFF);
    float* zh2   = (float*)((char*)d_ws + ZH2_OFF);
    float* zl2   = (float*)((char*)d_ws + ZL2_OFF);
    int*   qrows = (int*)((char*)d_ws + QROWS_OFF);
    int* cnt    = (int*)((char*)d_ws + CNT_OFF);
    int* offs   = (int*)((char*)d_ws + OFFS_OFF);
    int* cursor = (int*)((char*)d_ws + CURS_OFF);
    int* rowl   = (int*)((char*)d_ws + ROWL_OFF);
    float* lpart= (float*)((char*)d_ws + LPART_OFF);

    split_z<<<8192, 256, 0, stream>>>(z, zp, zh2, zl2);
    split_w<<<2048, 256, 0, stream>>>(w, wp, (unsigned*)&scal[2], (unsigned*)&scal[3]);
    score_h<<<dim3(128, 4), 512, 0, stream>>>(zp, wp, wsq, d12);
    fixup_kernel<<<8192, 256, 0, stream>>>(d12, zh2, zl2, scal, packed, thra,
                                           qrows, (int*)&scal[4]);
    refine_kernel<<<512, 256, 0, stream>>>(z, w, wsq, d12, thra, qrows,
                                           (const int*)&scal[4], packed);
    // aux arrays alias zp (dead after score_h) -> init only now
    hipMemsetAsync((void*)cnt, 0, K_N * sizeof(int), stream);
    count_kernel<<<B_N / 256, 256, 0, stream>>>(packed, cnt, idxout);
    scan_kernel<<<1, 256, 0, stream>>>(cnt, offs, cursor);
    scatter_ids<<<B_N / 256, 256, 0, stream>>>(packed, cursor, rowl);
    seg_accum<<<K_N, 256, 0, stream>>>(z, edw, ecs, offs, rowl, nedw_out, ncs_out);
    quant_loss<<<B_N, 256, 0, stream>>>(z, w, packed, qout, lpart);
    reduce2<<<1, 256, 0, stream>>>(ncs_out, lpart, nsum, loss_sum);
  } else {
    prep_nedw<<<4096, 256, 0, stream>>>((const float4*)edw, (float4*)nedw_out);
    score_argmin_mfma<<<dim3(B_N / 128, KSPLIT), 256, 0, stream>>>(z, w, wsq, packed);
    gather_scatter<<<B_N, 256, 0, stream>>>(z, w, packed, qout, idxout,
                                            ncs_out, nedw_out, loss_sum);
    reduce_n<<<1, 256, 0, stream>>>(ncs_out, nsum);
  }

  finalize<<<K_N * D_N / 256, 256, 0, stream>>>(ncs_out, nedw_out, nw_out,
                                                nsum, loss_sum, loss_out);
}

// Round 8
// 1414.345 us; speedup vs baseline: 1.4710x; 1.4710x over previous
//
#include <hip/hip_runtime.h>

#define B_N 32768
#define D_N 512
#define K_N 8192
#define EMA 0.99f
#define ONE_M_EMA 0.01f
#define EPS_ 1e-5f
#define CCOST 0.25f

// ws layout (fast path):
// [0, 262144)      : u64 packed[B_N] (low32 = idx)
// [262144, 294912) : float wsq[K_N]
// [294912, 294932) : scal[5]: loss_sum, n_sum, maxwl2, maxw2, qcount
// zp[16][32768][32] bf16-hi, swizzled        @ ZP_OFF
// wp[16][8192][32]                           @ WP_OFF
// dist12[128 entry][B] float4{v1,i1,v2,_}    @ DIST_OFF (entry-major, coalesced)
// thresh[B] f32 @ THR_OFF; zh2/zl2[B]; qrows[B]
#define ZP_OFF    295936ull
#define WP_OFF    33850368ull
#define DIST_OFF  42238976ull
#define THR_OFF   109347840ull
#define ZH2_OFF   109478912ull
#define ZL2_OFF   109609984ull
#define QROWS_OFF 109741056ull
#define WS_NEED   109872128ull
#define CNT_OFF    295936ull
#define OFFS_OFF   332800ull
#define CURS_OFF   365568ull
#define ROWL_OFF   398336ull
#define LPART_OFF  529408ull

typedef __attribute__((ext_vector_type(8))) short bf16x8;
typedef __attribute__((ext_vector_type(4))) float f32x4;

// ---------------------------------------------------------------- prep ----
__global__ __launch_bounds__(256) void prep_kernel(const float* __restrict__ w,
                                                   const float* __restrict__ ecs,
                                                   float* __restrict__ wsq,
                                                   float* __restrict__ ncs_out) {
  int row  = blockIdx.x * 4 + (threadIdx.x >> 6);
  int lane = threadIdx.x & 63;
  const float* p = w + (size_t)row * D_N + lane * 8;
  float4 a = *(const float4*)p;
  float4 b = *(const float4*)(p + 4);
  float s = a.x*a.x + a.y*a.y + a.z*a.z + a.w*a.w
          + b.x*b.x + b.y*b.y + b.z*b.z + b.w*b.w;
  #pragma unroll
  for (int off = 32; off; off >>= 1) s += __shfl_down(s, off);
  if (lane == 0) wsq[row] = s;

  int gid = blockIdx.x * 256 + threadIdx.x;           // fallback-path ncs init
  if (gid < K_N) ncs_out[gid] = EMA * ecs[gid];
}

__global__ __launch_bounds__(256) void prep_nedw(const float4* __restrict__ edw,
                                                 float4* __restrict__ nedw) {
  int i = blockIdx.x * 256 + threadIdx.x;
  float4 v = edw[i];
  v.x *= EMA; v.y *= EMA; v.z *= EMA; v.w *= EMA;
  nedw[i] = v;
}

// ------------------------------------------------------------ pre-split ---
__global__ __launch_bounds__(256) void split_z(const float* __restrict__ x,
                                               ushort* __restrict__ xp,
                                               float* __restrict__ zh2,
                                               float* __restrict__ zl2) {
  int g = blockIdx.x * 256 + threadIdx.x;
  int row = g >> 6, c = g & 63;
  const float* src = x + (size_t)row * 512 + c * 8;
  float v[8];
  *(float4*)&v[0] = *(const float4*)&src[0];
  *(float4*)&v[4] = *(const float4*)&src[4];
  uint hw[4]; float h2 = 0.f, l2 = 0.f;
  #pragma unroll
  for (int i = 0; i < 4; i++) {
    uint b0 = __float_as_uint(v[2*i]);
    uint b1 = __float_as_uint(v[2*i+1]);
    float h0 = __uint_as_float(b0 & 0xFFFF0000u);
    float h1 = __uint_as_float(b1 & 0xFFFF0000u);
    float r0 = v[2*i] - h0, r1 = v[2*i+1] - h1;
    hw[i] = (b0 >> 16) | (b1 & 0xFFFF0000u);
    h2 += h0*h0 + h1*h1;  l2 += r0*r0 + r1*r1;
  }
  int si = c >> 2;
  int p  = (c & 3) ^ ((row >> 1) & 3);
  size_t d0 = (size_t)si * (32768u * 32u) + (size_t)row * 32 + (size_t)p * 8;
  *(uint4*)&xp[d0] = (uint4){hw[0], hw[1], hw[2], hw[3]};
  #pragma unroll
  for (int off = 32; off; off >>= 1) { h2 += __shfl_down(h2, off); l2 += __shfl_down(l2, off); }
  if (c == 0) { zh2[row] = h2; zl2[row] = l2; }
}

__global__ __launch_bounds__(256) void split_w(const float* __restrict__ x,
                                               ushort* __restrict__ xp,
                                               unsigned* __restrict__ maxwl2,
                                               unsigned* __restrict__ maxw2) {
  int g = blockIdx.x * 256 + threadIdx.x;
  int row = g >> 6, c = g & 63;
  const float* src = x + (size_t)row * 512 + c * 8;
  float v[8];
  *(float4*)&v[0] = *(const float4*)&src[0];
  *(float4*)&v[4] = *(const float4*)&src[4];
  uint hw[4]; float w2 = 0.f, l2 = 0.f;
  #pragma unroll
  for (int i = 0; i < 4; i++) {
    uint b0 = __float_as_uint(v[2*i]);
    uint b1 = __float_as_uint(v[2*i+1]);
    float h0 = __uint_as_float(b0 & 0xFFFF0000u);
    float h1 = __uint_as_float(b1 & 0xFFFF0000u);
    float r0 = v[2*i] - h0, r1 = v[2*i+1] - h1;
    hw[i] = (b0 >> 16) | (b1 & 0xFFFF0000u);
    w2 += v[2*i]*v[2*i] + v[2*i+1]*v[2*i+1];  l2 += r0*r0 + r1*r1;
  }
  int si = c >> 2;
  int p  = (c & 3) ^ ((row >> 1) & 3);
  size_t d0 = (size_t)si * (8192u * 32u) + (size_t)row * 32 + (size_t)p * 8;
  *(uint4*)&xp[d0] = (uint4){hw[0], hw[1], hw[2], hw[3]};
  #pragma unroll
  for (int off = 32; off; off >>= 1) { w2 += __shfl_down(w2, off); l2 += __shfl_down(l2, off); }
  if (c == 0) {
    atomicMax(maxwl2, __float_as_uint(l2));
    atomicMax(maxw2,  __float_as_uint(w2));
  }
}

// --------------------------------------------------------- score (hi-hi) --
constexpr int COLT2 = 8;

#define GLDS(SRC, DST) __builtin_amdgcn_global_load_lds((const unsigned int*)(SRC), (unsigned int*)(DST), 16, 0, 0)

#define PHASE(AC, BC, AL, BL, G)                                               \
  {                                                                            \
    const int g_ = (G);                                                        \
    if (g_ + 1 <= 127) {                                                       \
      const char* Ab_ = (const char*)As[(g_ + 1) & 3] + aoff;                  \
      const char* Bb_ = (const char*)Bs[(g_ + 1) & 3] + boff;                  \
      _Pragma("unroll")                                                        \
      for (int i_ = 0; i_ < 8; i_++) AL[i_] = *(const bf16x8*)(Ab_ + i_ * 1024);\
      _Pragma("unroll")                                                        \
      for (int j_ = 0; j_ < 4; j_++) BL[j_] = *(const bf16x8*)(Bb_ + j_ * 1024);\
    }                                                                          \
    if (g_ + 4 <= 127) {                                                       \
      const int slotF_ = sf & 3;                                               \
      GLDS(zA + (size_t)sf * 2097152,        (char*)As[slotF_] + t * 16);      \
      GLDS(zA + (size_t)sf * 2097152 + 8192, (char*)As[slotF_] + 8192 + t * 16);\
      const size_t wOfs_ = (size_t)sf * 524288 + (size_t)ctf * 16384;          \
      GLDS(wB + wOfs_,        (char*)Bs[slotF_] + t * 16);                     \
      GLDS(wB + wOfs_ + 8192, (char*)Bs[slotF_] + 8192 + t * 16);              \
      sf++; if (sf == 16) { sf = 0; ctf++; }                                   \
    }                                                                          \
    __builtin_amdgcn_s_setprio(1);                                             \
    _Pragma("unroll")                                                          \
    for (int i_ = 0; i_ < 8; i_++)                                             \
      _Pragma("unroll")                                                        \
      for (int j_ = 0; j_ < 4; j_++)                                           \
        acc[i_][j_] = __builtin_amdgcn_mfma_f32_16x16x32_bf16(AC[i_], BC[j_],  \
                                                        acc[i_][j_], 0, 0, 0); \
    __builtin_amdgcn_s_setprio(0);                                             \
    asm volatile("s_waitcnt lgkmcnt(0)" ::: "memory");                         \
    if (g_ <= 123)      { asm volatile("s_waitcnt vmcnt(8)" ::: "memory"); }   \
    else if (g_ == 124) { asm volatile("s_waitcnt vmcnt(4)" ::: "memory"); }   \
    else if (g_ == 125) { asm volatile("s_waitcnt vmcnt(0)" ::: "memory"); }   \
    __builtin_amdgcn_s_barrier();                                              \
    __builtin_amdgcn_sched_barrier(0);                                         \
  }

__global__ __launch_bounds__(512, 2) void score_h(
    const ushort* __restrict__ zp, const ushort* __restrict__ wp,
    const float* __restrict__ wsq, float4* __restrict__ dist12) {
  __shared__ ushort As[4][8192];
  __shared__ ushort Bs[4][8192];
  __shared__ float wsqs[2048];
  __shared__ float4 stg[4][256];       // epilogue transpose buffer (16 KB)

  const int t = threadIdx.x, lane = t & 63, wid = t >> 6;
  const int wm = wid >> 2, wn = wid & 3;
  const int l15 = lane & 15, lg = (lane >> 4) & 3;
  const int row0 = blockIdx.x * 256;
  const int cg0  = blockIdx.y * 2048;

  const char* zA = (const char*)zp + ((size_t)(row0 + (t >> 2)) * 64 + (size_t)(t & 3) * 16);
  const char* wB = (const char*)wp + ((size_t)(cg0  + (t >> 2)) * 64 + (size_t)(t & 3) * 16);

  const int swz  = (l15 >> 1) & 3;
  const int aoff = (wm * 128 + l15) * 64 + ((lg ^ swz) * 16);
  const int boff = (wn * 64  + l15) * 64 + ((lg ^ swz) * 16);

  { float4 v = *(const float4*)&wsq[cg0 + t * 4]; *(float4*)&wsqs[t * 4] = v; }
  __syncthreads();

  #pragma unroll
  for (int s0 = 0; s0 < 4; s0++) {
    GLDS(zA + (size_t)s0 * 2097152,        (char*)As[s0] + t * 16);
    GLDS(zA + (size_t)s0 * 2097152 + 8192, (char*)As[s0] + 8192 + t * 16);
    GLDS(wB + (size_t)s0 * 524288,         (char*)Bs[s0] + t * 16);
    GLDS(wB + (size_t)s0 * 524288 + 8192,  (char*)Bs[s0] + 8192 + t * 16);
  }
  asm volatile("s_waitcnt vmcnt(8)" ::: "memory");
  __builtin_amdgcn_s_barrier();
  __builtin_amdgcn_sched_barrier(0);

  bf16x8 aE[8], bE[4], aO[8], bO[4];
  #pragma unroll
  for (int i = 0; i < 8; i++) aE[i] = *(const bf16x8*)((const char*)As[0] + aoff + i * 1024);
  #pragma unroll
  for (int j = 0; j < 4; j++) bE[j] = *(const bf16x8*)((const char*)Bs[0] + boff + j * 1024);
  asm volatile("s_waitcnt lgkmcnt(0)" ::: "memory");
  __builtin_amdgcn_s_barrier();
  __builtin_amdgcn_sched_barrier(0);

  int sf = 4, ctf = 0;

  for (int ct = 0; ct < COLT2; ct++) {
    f32x4 acc[8][4];
    #pragma unroll
    for (int i = 0; i < 8; i++)
      #pragma unroll
      for (int j = 0; j < 4; j++) acc[i][j] = (f32x4){0.f, 0.f, 0.f, 0.f};

    for (int s = 0; s < 16; s += 2) {
      const int g = ct * 16 + s;
      PHASE(aE, bE, aO, bO, g)
      PHASE(aO, bO, aE, bE, g + 1)
    }

    // ---- epilogue: per-granule (v1,i1,v2) -> LDS transpose -> coalesced write
    const int tileG = blockIdx.y * 8 + ct;
    #pragma unroll
    for (int e = 0; e < 32; e++) {
      const int i = e >> 2, r = e & 3;
      float b1 = 3.4e38f, b2 = 3.4e38f; int bi = 0x7FFFFFFF;
      #pragma unroll
      for (int j = 0; j < 4; j++) {
        float d  = wsqs[ct * 256 + wn * 64 + j * 16 + l15] - 2.0f * acc[i][j][r];
        int cc   = cg0 + ct * 256 + wn * 64 + j * 16 + l15;
        if (d < b1)      { b2 = b1; b1 = d; bi = cc; }
        else if (d < b2) { b2 = d; }
      }
      #pragma unroll
      for (int m = 1; m < 16; m <<= 1) {
        float o1 = __shfl_xor(b1, m, 64);
        int   oi = __shfl_xor(bi, m, 64);
        float o2 = __shfl_xor(b2, m, 64);
        bool tb = (o1 < b1) || (o1 == b1 && oi < bi);
        float lose = tb ? b1 : o1;
        b2 = fminf(fminf(b2, o2), lose);
        b1 = tb ? o1 : b1; bi = tb ? oi : bi;
      }
      if (l15 == 0) {
        const int rl = wm * 128 + (e >> 2) * 16 + lg * 4 + (e & 3);
        stg[wn][rl] = (float4){b1, __int_as_float(bi), b2, 0.f};
      }
    }
    asm volatile("s_waitcnt lgkmcnt(0)" ::: "memory");
    __builtin_amdgcn_s_barrier();
    #pragma unroll
    for (int it2 = 0; it2 < 2; it2++) {
      int idx = it2 * 512 + t;
      int ee = idx >> 8, rl = idx & 255;
      float4 v = stg[ee][rl];
      dist12[(size_t)(tileG * 4 + ee) * 32768 + row0 + rl] = v;
    }
    __builtin_amdgcn_s_barrier();
  }
}

// ------------------------------------------- fixup2: lane-owns-row scan ---
__global__ __launch_bounds__(256) void fixup2(
    const float4* __restrict__ dist12, const float* __restrict__ zh2,
    const float* __restrict__ zl2, const float* __restrict__ scal,
    unsigned long long* __restrict__ packed, float* __restrict__ thra,
    int* __restrict__ qrows, int* __restrict__ qcount) {
  int t = threadIdx.x, wv = t >> 6, lane = t & 63;
  int row = (blockIdx.x * 4 + wv) * 64 + lane;
  float v1 = 3.4e38f, v2 = 3.4e38f; int i1 = 0x7FFFFFFF;
  const float4* base = dist12 + row;
  for (int e = 0; e < 128; e++) {
    float4 v = base[(size_t)e * 32768];
    if (v.x < v1) { v2 = fminf(v1, fminf(v2, v.z)); v1 = v.x; i1 = __float_as_int(v.y); }
    else          { v2 = fminf(v2, v.x); }
  }
  // |dhat - D| <= B = 2(||zh|| max||wl|| + ||zl|| max||w||); candidates within 2B
  float B = 2.0f * (sqrtf(zh2[row]) * sqrtf(scal[2]) + sqrtf(zl2[row]) * sqrtf(scal[3]));
  float thr = v1 + 2.05f * B + 1e-5f;
  bool q = !(v2 > thr);
  if (!q) packed[row] = (unsigned long long)(unsigned)i1;
  unsigned long long mask = __ballot(q);
  int cnt = __popcll(mask);
  int basep = 0;
  if (lane == 0 && cnt) basep = atomicAdd(qcount, cnt);
  basep = __shfl(basep, 0);
  if (q) {
    int pos = basep + __popcll(mask & ((1ull << lane) - 1ull));
    qrows[pos] = row;
    thra[row] = thr;
  }
}

// ------------------------------------------------ refine2: exact f32 dots -
__device__ __forceinline__ float exact_dist(const float* __restrict__ w,
                                            const float* __restrict__ wsq,
                                            float4 za, float4 zb, int ki, int lane) {
  const float* wr = w + (size_t)ki * 512 + lane * 8;
  float4 wa = *(const float4*)wr;
  float4 wb = *(const float4*)(wr + 4);
  float s = za.x*wa.x + za.y*wa.y + za.z*wa.z + za.w*wa.w
          + zb.x*wb.x + zb.y*wb.y + zb.z*wb.z + zb.w*wb.w;
  #pragma unroll
  for (int m = 1; m < 64; m <<= 1) s += __shfl_xor(s, m, 64);
  return wsq[ki] - 2.0f * s;
}

__global__ __launch_bounds__(256) void refine2(
    const float* __restrict__ z, const float* __restrict__ w,
    const float* __restrict__ wsq, const float4* __restrict__ dist12,
    const float* __restrict__ thra, const int* __restrict__ qrows,
    const int* __restrict__ qcount, unsigned long long* __restrict__ packed) {
  __shared__ float zs[512];
  __shared__ float bd[4];
  __shared__ int bix[4];
  int t = threadIdx.x, wv = t >> 6, lane = t & 63;
  int n = qcount[0];
  for (int it = blockIdx.x; it < n; it += gridDim.x) {
    int row = qrows[it];
    float thr = thra[row];
    zs[t]       = z[(size_t)row * 512 + t];
    zs[t + 256] = z[(size_t)row * 512 + 256 + t];
    __syncthreads();
    float4 za = *(const float4*)&zs[lane * 8];
    float4 zb = *(const float4*)&zs[lane * 8 + 4];
    int e = wv + 4 * (lane & 31);                // wave wv owns entries e == wv mod 4
    float4 ev = dist12[(size_t)e * 32768 + row];
    unsigned long long mc = __ballot(ev.x <= thr) & 0xFFFFFFFFull;
    unsigned long long ms = __ballot(ev.z <= thr) & 0xFFFFFFFFull;
    float bestd = 3.4e38f; int besti = 0x7FFFFFFF;
    while (mc) {                                 // single candidates
      int src = __ffsll(mc) - 1; mc &= mc - 1;
      int ki = __shfl(__float_as_int(ev.y), src);
      float d = exact_dist(w, wsq, za, zb, ki, lane);
      if (d < bestd || (d == bestd && ki < besti)) { bestd = d; besti = ki; }
    }
    while (ms) {                                 // rare: >=2 cands in a granule
      int src = __ffsll(ms) - 1; ms &= ms - 1;
      int e2 = wv + 4 * src;
      int col0 = (e2 >> 2) * 256 + (e2 & 3) * 64;
      for (int q = 0; q < 64; q++) {
        int ki = col0 + q;
        float d = exact_dist(w, wsq, za, zb, ki, lane);
        if (d < bestd || (d == bestd && ki < besti)) { bestd = d; besti = ki; }
      }
    }
    if (lane == 0) { bd[wv] = bestd; bix[wv] = besti; }
    __syncthreads();
    if (t == 0) {
      float B1 = bd[0]; int I1 = bix[0];
      #pragma unroll
      for (int k2 = 1; k2 < 4; k2++)
        if (bd[k2] < B1 || (bd[k2] == B1 && bix[k2] < I1)) { B1 = bd[k2]; I1 = bix[k2]; }
      packed[row] = (unsigned long long)(unsigned)I1;
    }
    __syncthreads();
  }
}

// ---------------------------------------- fallback score (round-2 kernel) --
constexpr int LDP = 40;
constexpr int KSPLIT = 8, COLT = K_N / KSPLIT / 128;
__device__ __forceinline__ void stage16(const float* __restrict__ g,
                                        ushort* __restrict__ h,
                                        ushort* __restrict__ l) {
  float v[16];
  *(float4*)&v[0]  = *(const float4*)&g[0];
  *(float4*)&v[4]  = *(const float4*)&g[4];
  *(float4*)&v[8]  = *(const float4*)&g[8];
  *(float4*)&v[12] = *(const float4*)&g[12];
  uint hw[8], lw[8];
  #pragma unroll
  for (int i = 0; i < 8; i++) {
    uint b0 = __float_as_uint(v[2*i]);
    uint b1 = __float_as_uint(v[2*i+1]);
    float r0 = v[2*i]   - __uint_as_float(b0 & 0xFFFF0000u);
    float r1 = v[2*i+1] - __uint_as_float(b1 & 0xFFFF0000u);
    hw[i] = (b0 >> 16) | (b1 & 0xFFFF0000u);
    lw[i] = (__float_as_uint(r0) >> 16) | (__float_as_uint(r1) & 0xFFFF0000u);
  }
  ((uint4*)h)[0] = *(uint4*)&hw[0];
  ((uint4*)h)[1] = *(uint4*)&hw[4];
  ((uint4*)l)[0] = *(uint4*)&lw[0];
  ((uint4*)l)[1] = *(uint4*)&lw[4];
}

__global__ __launch_bounds__(256, 2) void score_argmin_mfma(
    const float* __restrict__ z, const float* __restrict__ w,
    const float* __restrict__ wsq, unsigned long long* __restrict__ packed) {
  __shared__ ushort Ah[128][LDP];
  __shared__ ushort Al[128][LDP];
  __shared__ ushort Bh[128][LDP];
  __shared__ ushort Bl[128][LDP];
  const int t = threadIdx.x, lane = t & 63, wid = t >> 6;
  const int wm = wid >> 1, wn = wid & 1;
  const int l15 = lane & 15, lg = lane >> 4;
  const int row0 = blockIdx.x * 128;
  const int ks0  = blockIdx.y * (K_N / KSPLIT);
  const int srow = t >> 1, skq = (t & 1) * 16;
  float rmin[16]; int ridx[16];
  #pragma unroll
  for (int e = 0; e < 16; e++) { rmin[e] = 3.4e38f; ridx[e] = 0; }
  for (int ct = 0; ct < COLT; ct++) {
    const int c0 = ks0 + ct * 128;
    f32x4 acc[4][4];
    #pragma unroll
    for (int i = 0; i < 4; i++)
      #pragma unroll
      for (int j = 0; j < 4; j++) acc[i][j] = (f32x4){0.f, 0.f, 0.f, 0.f};
    for (int k0 = 0; k0 < D_N; k0 += 32) {
      __syncthreads();
      stage16(&z[(size_t)(row0 + srow) * D_N + k0 + skq], &Ah[srow][skq], &Al[srow][skq]);
      stage16(&w[(size_t)(c0   + srow) * D_N + k0 + skq], &Bh[srow][skq], &Bl[srow][skq]);
      __syncthreads();
      bf16x8 ah[4], al[4], bh[4], bl[4];
      #pragma unroll
      for (int i = 0; i < 4; i++) {
        ah[i] = *(const bf16x8*)&Ah[wm*64 + i*16 + l15][lg*8];
        al[i] = *(const bf16x8*)&Al[wm*64 + i*16 + l15][lg*8];
        bh[i] = *(const bf16x8*)&Bh[wn*64 + i*16 + l15][lg*8];
        bl[i] = *(const bf16x8*)&Bl[wn*64 + i*16 + l15][lg*8];
      }
      #pragma unroll
      for (int i = 0; i < 4; i++)
        #pragma unroll
        for (int j = 0; j < 4; j++) {
          acc[i][j] = __builtin_amdgcn_mfma_f32_16x16x32_bf16(ah[i], bh[j], acc[i][j], 0, 0, 0);
          acc[i][j] = __builtin_amdgcn_mfma_f32_16x16x32_bf16(ah[i], bl[j], acc[i][j], 0, 0, 0);
          acc[i][j] = __builtin_amdgcn_mfma_f32_16x16x32_bf16(al[i], bh[j], acc[i][j], 0, 0, 0);
        }
    }
    float wq[4];
    #pragma unroll
    for (int j = 0; j < 4; j++) wq[j] = wsq[c0 + wn*64 + j*16 + l15];
    #pragma unroll
    for (int i = 0; i < 4; i++)
      #pragma unroll
      for (int r = 0; r < 4; r++) {
        const int e = i * 4 + r;
        #pragma unroll
        for (int j = 0; j < 4; j++) {
          float dist = wq[j] - 2.0f * acc[i][j][r];
          if (dist < rmin[e]) { rmin[e] = dist; ridx[e] = c0 + wn*64 + j*16 + l15; }
        }
      }
  }
  #pragma unroll
  for (int e = 0; e < 16; e++) {
    float v = rmin[e]; int ix = ridx[e];
    #pragma unroll
    for (int m = 1; m < 16; m <<= 1) {
      float ov = __shfl_xor(v, m, 64);
      int   oi = __shfl_xor(ix, m, 64);
      if (ov < v || (ov == v && oi < ix)) { v = ov; ix = oi; }
    }
    rmin[e] = v; ridx[e] = ix;
  }
  const int s = l15;
  float bv = 0.f; int bi = 0;
  #pragma unroll
  for (int e = 0; e < 16; e++) {
    bool p = (e == s);
    bv = p ? rmin[e] : bv;
    bi = p ? ridx[e] : bi;
  }
  unsigned u = __float_as_uint(bv);
  u = (u & 0x80000000u) ? ~u : (u | 0x80000000u);
  unsigned long long key = ((unsigned long long)u << 32) | (unsigned)bi;
  atomicMin(&packed[row0 + wm*64 + (s >> 2)*16 + lg*4 + (s & 3)], key);
}

// ------------------------------------------- counting-sort segment-sum ----
__global__ __launch_bounds__(256) void count_kernel(
    const unsigned long long* __restrict__ packed, int* __restrict__ cnt,
    float* __restrict__ idxout) {
  int row = blockIdx.x * 256 + threadIdx.x;
  int idx = (int)(packed[row] & 0xFFFFFFFFull);
  idxout[row] = (float)idx;
  atomicAdd(&cnt[idx], 1);
}

__global__ __launch_bounds__(256) void scan_kernel(const int* __restrict__ cnt,
                                                   int* __restrict__ offs,
                                                   int* __restrict__ cursor) {
  int t = threadIdx.x;
  int base = t * 32;
  int local[32];
  int s = 0;
  #pragma unroll
  for (int i = 0; i < 32; i++) { local[i] = s; s += cnt[base + i]; }
  __shared__ int ps[257];
  ps[t + 1] = s;
  if (t == 0) ps[0] = 0;
  __syncthreads();
  if (t == 0) { for (int i = 1; i <= 256; i++) ps[i] += ps[i - 1]; }
  __syncthreads();
  int e = ps[t];
  #pragma unroll
  for (int i = 0; i < 32; i++) {
    int o = e + local[i];
    offs[base + i] = o; cursor[base + i] = o;
  }
  if (t == 255) offs[8192] = ps[256];
}

__global__ __launch_bounds__(256) void scatter_ids(
    const unsigned long long* __restrict__ packed, int* __restrict__ cursor,
    int* __restrict__ rowlist) {
  int row = blockIdx.x * 256 + threadIdx.x;
  int idx = (int)(packed[row] & 0xFFFFFFFFull);
  int pos = atomicAdd(&cursor[idx], 1);
  rowlist[pos] = row;
}

__global__ __launch_bounds__(256) void seg_accum(
    const float* __restrict__ z, const float* __restrict__ edw,
    const float* __restrict__ ecs, const int* __restrict__ offs,
    const int* __restrict__ rowlist, float* __restrict__ nedw_out,
    float* __restrict__ ncs_out) {
  int k = blockIdx.x, t = threadIdx.x;
  int s0 = offs[k], s1 = offs[k + 1];
  float ax = 0.f, ay = 0.f;
  for (int r = s0; r < s1; r++) {
    int row = rowlist[r];
    float2 zv = *(const float2*)&z[(size_t)row * D_N + t * 2];
    ax += zv.x; ay += zv.y;
  }
  float2 ev = *(const float2*)&edw[(size_t)k * D_N + t * 2];
  float2 o;
  o.x = EMA * ev.x + ONE_M_EMA * ax;
  o.y = EMA * ev.y + ONE_M_EMA * ay;
  *(float2*)&nedw_out[(size_t)k * D_N + t * 2] = o;
  if (t == 0) ncs_out[k] = EMA * ecs[k] + ONE_M_EMA * (float)(s1 - s0);
}

// ------------------------------------------------ quantize + loss partial --
__global__ __launch_bounds__(256) void quant_loss(
    const float* __restrict__ z, const float* __restrict__ w,
    const unsigned long long* __restrict__ packed,
    float* __restrict__ qout, float* __restrict__ lpart) {
  int row = blockIdx.x, t = threadIdx.x;
  int idx = (int)(packed[row] & 0xFFFFFFFFull);
  float2 zv = *(const float2*)&z[(size_t)row * D_N + t * 2];
  float2 wv = *(const float2*)&w[(size_t)idx * D_N + t * 2];
  float2 q;
  q.x = zv.x + (wv.x - zv.x);
  q.y = zv.y + (wv.y - zv.y);
  *(float2*)&qout[(size_t)row * D_N + t * 2] = q;
  float dx = zv.x - wv.x, dy = zv.y - wv.y;
  float s = dx * dx + dy * dy;
  #pragma unroll
  for (int off = 32; off; off >>= 1) s += __shfl_down(s, off);
  __shared__ float part[4];
  if ((t & 63) == 0) part[t >> 6] = s;
  __syncthreads();
  if (t == 0) lpart[row] = part[0] + part[1] + part[2] + part[3];
}

// ------------------------------------------------------------- reductions -
__global__ __launch_bounds__(256) void reduce2(const float* __restrict__ ncs_out,
                                               const float* __restrict__ lpart,
                                               float* __restrict__ nsum,
                                               float* __restrict__ loss_sum) {
  int t = threadIdx.x;
  float s1 = 0.f, s2 = 0.f;
  for (int i = t; i < K_N; i += 256) s1 += ncs_out[i];
  for (int i = t; i < B_N; i += 256) s2 += lpart[i];
  #pragma unroll
  for (int off = 32; off; off >>= 1) {
    s1 += __shfl_down(s1, off);
    s2 += __shfl_down(s2, off);
  }
  __shared__ float p1[4], p2[4];
  if ((t & 63) == 0) { p1[t >> 6] = s1; p2[t >> 6] = s2; }
  __syncthreads();
  if (t == 0) {
    nsum[0]     = p1[0] + p1[1] + p1[2] + p1[3];
    loss_sum[0] = p2[0] + p2[1] + p2[2] + p2[3];
  }
}

// fallback-path kernels
__global__ __launch_bounds__(256) void gather_scatter(
    const float* __restrict__ z, const float* __restrict__ w,
    const unsigned long long* __restrict__ packed,
    float* __restrict__ qout, float* __restrict__ idxout,
    float* __restrict__ ncs_out, float* __restrict__ nedw_out,
    float* __restrict__ loss_sum) {
  int row = blockIdx.x;
  int t   = threadIdx.x;
  int idx = (int)(packed[row] & 0xFFFFFFFFull);
  float2 zv = *(const float2*)&z[(size_t)row * D_N + t * 2];
  float2 wv = *(const float2*)&w[(size_t)idx * D_N + t * 2];
  float2 q;
  q.x = zv.x + (wv.x - zv.x);
  q.y = zv.y + (wv.y - zv.y);
  *(float2*)&qout[(size_t)row * D_N + t * 2] = q;
  float dx = zv.x - wv.x, dy = zv.y - wv.y;
  float s = dx*dx + dy*dy;
  #pragma unroll
  for (int off = 32; off; off >>= 1) s += __shfl_down(s, off);
  __shared__ float part[4];
  if ((t & 63) == 0) part[t >> 6] = s;
  __syncthreads();
  if (t == 0) {
    atomicAdd(loss_sum, part[0] + part[1] + part[2] + part[3]);
    atomicAdd(&ncs_out[idx], ONE_M_EMA);
    idxout[row] = (float)idx;
  }
  atomicAdd(&nedw_out[(size_t)idx * D_N + t*2],     ONE_M_EMA * zv.x);
  atomicAdd(&nedw_out[(size_t)idx * D_N + t*2 + 1], ONE_M_EMA * zv.y);
}

__global__ __launch_bounds__(256) void reduce_n(const float* __restrict__ ncs_out,
                                                float* __restrict__ nsum) {
  int t = threadIdx.x;
  float s = 0.f;
  for (int i = t; i < K_N; i += 256) s += ncs_out[i];
  #pragma unroll
  for (int off = 32; off; off >>= 1) s += __shfl_down(s, off);
  __shared__ float part[4];
  if ((t & 63) == 0) part[t >> 6] = s;
  __syncthreads();
  if (t == 0) nsum[0] = part[0] + part[1] + part[2] + part[3];
}

__global__ __launch_bounds__(256) void finalize(
    const float* __restrict__ ncs_out, const float* __restrict__ nedw_out,
    float* __restrict__ nw_out, const float* __restrict__ nsum,
    const float* __restrict__ loss_sum, float* __restrict__ loss_out) {
  size_t i = (size_t)blockIdx.x * 256 + threadIdx.x;
  float n = nsum[0];
  int k = (int)(i >> 9);
  float nv = ncs_out[k];
  float cs = (nv + EPS_) / (n + K_N * EPS_) * n;
  nw_out[i] = nedw_out[i] / cs;
  if (i == 0) loss_out[0] = CCOST * loss_sum[0] / (float)((size_t)B_N * D_N);
}

// ------------------------------------------------------------------ launch -
extern "C" void kernel_launch(void* const* d_in, const int* in_sizes, int n_in,
                              void* d_out, int out_size, void* d_ws, size_t ws_size,
                              hipStream_t stream) {
  const float* z   = (const float*)d_in[0];
  const float* w   = (const float*)d_in[1];
  const float* ecs = (const float*)d_in[2];
  const float* edw = (const float*)d_in[3];

  float* out      = (float*)d_out;
  float* qout     = out;
  float* idxout   = out + (size_t)B_N * D_N;
  float* loss_out = idxout + B_N;
  float* nw_out   = loss_out + 1;
  float* ncs_out  = nw_out + (size_t)K_N * D_N;
  float* nedw_out = ncs_out + K_N;

  unsigned long long* packed = (unsigned long long*)d_ws;
  float* wsq      = (float*)((char*)d_ws + 262144);
  float* scal     = (float*)((char*)d_ws + 294912);  // loss,n,maxwl2,maxw2,qcount
  float* loss_sum = scal;
  float* nsum     = scal + 1;

  hipMemsetAsync(d_ws, 0xFF, 262144, stream);
  hipMemsetAsync((void*)scal, 0, 20, stream);

  prep_kernel<<<2048, 256, 0, stream>>>(w, ecs, wsq, ncs_out);

  if (ws_size >= WS_NEED) {
    ushort* zp   = (ushort*)((char*)d_ws + ZP_OFF);
    ushort* wp   = (ushort*)((char*)d_ws + WP_OFF);
    float4* d12  = (float4*)((char*)d_ws + DIST_OFF);
    float* thra  = (float*)((char*)d_ws + THR_OFF);
    float* zh2   = (float*)((char*)d_ws + ZH2_OFF);
    float* zl2   = (float*)((char*)d_ws + ZL2_OFF);
    int*   qrows = (int*)((char*)d_ws + QROWS_OFF);
    int* cnt    = (int*)((char*)d_ws + CNT_OFF);
    int* offs   = (int*)((char*)d_ws + OFFS_OFF);
    int* cursor = (int*)((char*)d_ws + CURS_OFF);
    int* rowl   = (int*)((char*)d_ws + ROWL_OFF);
    float* lpart= (float*)((char*)d_ws + LPART_OFF);

    split_z<<<8192, 256, 0, stream>>>(z, zp, zh2, zl2);
    split_w<<<2048, 256, 0, stream>>>(w, wp, (unsigned*)&scal[2], (unsigned*)&scal[3]);
    score_h<<<dim3(128, 4), 512, 0, stream>>>(zp, wp, wsq, d12);
    fixup2<<<128, 256, 0, stream>>>(d12, zh2, zl2, scal, packed, thra,
                                    qrows, (int*)&scal[4]);
    refine2<<<1024, 256, 0, stream>>>(z, w, wsq, d12, thra, qrows,
                                      (const int*)&scal[4], packed);
    // aux arrays alias zp (dead after score_h) -> init only now
    hipMemsetAsync((void*)cnt, 0, K_N * sizeof(int), stream);
    count_kernel<<<B_N / 256, 256, 0, stream>>>(packed, cnt, idxout);
    scan_kernel<<<1, 256, 0, stream>>>(cnt, offs, cursor);
    scatter_ids<<<B_N / 256, 256, 0, stream>>>(packed, cursor, rowl);
    seg_accum<<<K_N, 256, 0, stream>>>(z, edw, ecs, offs, rowl, nedw_out, ncs_out);
    quant_loss<<<B_N, 256, 0, stream>>>(z, w, packed, qout, lpart);
    reduce2<<<1, 256, 0, stream>>>(ncs_out, lpart, nsum, loss_sum);
  } else {
    prep_nedw<<<4096, 256, 0, stream>>>((const float4*)edw, (float4*)nedw_out);
    score_argmin_mfma<<<dim3(B_N / 128, KSPLIT), 256, 0, stream>>>(z, w, wsq, packed);
    gather_scatter<<<B_N, 256, 0, stream>>>(z, w, packed, qout, idxout,
                                            ncs_out, nedw_out, loss_sum);
    reduce_n<<<1, 256, 0, stream>>>(ncs_out, nsum);
  }

  finalize<<<K_N * D_N / 256, 256, 0, stream>>>(ncs_out, nedw_out, nw_out,
                                                nsum, loss_sum, loss_out);
}

// Round 9
// 1102.618 us; speedup vs baseline: 1.8869x; 1.2827x over previous
//
#include <hip/hip_runtime.h>

#define B_N 32768
#define D_N 512
#define K_N 8192
#define EMA 0.99f
#define ONE_M_EMA 0.01f
#define EPS_ 1e-5f
#define CCOST 0.25f

// ws layout (fast path):
// [0, 262144)            : u64 packed[B_N]  (low32 = idx), init 0xFF
// [262144, 294912)       : float wsq[K_N]
// [294912, 294920)       : float loss_sum, n_sum
// [295936, +100663296)   : ushort zp[48][32768][32]  slice-major bf16, chunk-XOR swizzled
// [100959232, +25165824) : ushort wp[48][8192][32]
#define ZP_OFF 295936ull
#define WP_OFF 100959232ull
#define WS_NEED (WP_OFF + 25165824ull)
#define CNT_OFF    295936ull
#define OFFS_OFF   332800ull
#define CURS_OFF   365568ull
#define ROWL_OFF   398336ull
#define LPART_OFF  529408ull

typedef __attribute__((ext_vector_type(8))) short bf16x8;
typedef __attribute__((ext_vector_type(4))) float f32x4;

// ---------------------------------------------------------------- prep ----
__global__ __launch_bounds__(256) void prep_kernel(const float* __restrict__ w,
                                                   const float* __restrict__ ecs,
                                                   float* __restrict__ wsq,
                                                   float* __restrict__ ncs_out) {
  int row  = blockIdx.x * 4 + (threadIdx.x >> 6);
  int lane = threadIdx.x & 63;
  const float* p = w + (size_t)row * D_N + lane * 8;
  float4 a = *(const float4*)p;
  float4 b = *(const float4*)(p + 4);
  float s = a.x*a.x + a.y*a.y + a.z*a.z + a.w*a.w
          + b.x*b.x + b.y*b.y + b.z*b.z + b.w*b.w;
  #pragma unroll
  for (int off = 32; off; off >>= 1) s += __shfl_down(s, off);
  if (lane == 0) wsq[row] = s;

  int gid = blockIdx.x * 256 + threadIdx.x;           // fallback-path ncs init
  if (gid < K_N) ncs_out[gid] = EMA * ecs[gid];
}

__global__ __launch_bounds__(256) void prep_nedw(const float4* __restrict__ edw,
                                                 float4* __restrict__ nedw) {
  int i = blockIdx.x * 256 + threadIdx.x;
  float4 v = edw[i];
  v.x *= EMA; v.y *= EMA; v.z *= EMA; v.w *= EMA;
  nedw[i] = v;
}

// ------------------------------------------------------------ pre-split ---
// x[R][512] f32 -> xp[48][R][32] bf16 slice-major; slice s = sec*16 + (d>>5).
// 16B chunk stored at (c ^ ((row>>1)&3)) -- ds_read-side XOR swizzle baked in.
// mode 0 (z): sections [hi|hi|lo]; mode 1 (w): [hi|lo|hi].
__global__ __launch_bounds__(256) void split_pack(const float* __restrict__ x,
                                                  ushort* __restrict__ xp,
                                                  int R, int mode) {
  int g   = blockIdx.x * 256 + threadIdx.x;
  int row = g >> 6, c = g & 63;
  const float* src = x + (size_t)row * 512 + c * 8;
  float v[8];
  *(float4*)&v[0] = *(const float4*)&src[0];
  *(float4*)&v[4] = *(const float4*)&src[4];
  uint hw[4], lw[4];
  #pragma unroll
  for (int i = 0; i < 4; i++) {
    uint b0 = __float_as_uint(v[2*i]);
    uint b1 = __float_as_uint(v[2*i+1]);
    float r0 = v[2*i]   - __uint_as_float(b0 & 0xFFFF0000u);
    float r1 = v[2*i+1] - __uint_as_float(b1 & 0xFFFF0000u);
    hw[i] = (b0 >> 16) | (b1 & 0xFFFF0000u);
    lw[i] = (__float_as_uint(r0) >> 16) | (__float_as_uint(r1) & 0xFFFF0000u);
  }
  uint4 H = {hw[0], hw[1], hw[2], hw[3]};
  uint4 L = {lw[0], lw[1], lw[2], lw[3]};
  int si  = c >> 2;
  int p   = (c & 3) ^ ((row >> 1) & 3);
  size_t sstr = (size_t)R * 32;
  size_t base = (size_t)row * 32 + (size_t)p * 8;
  size_t d0 = (size_t)(si)      * sstr + base;
  size_t d1 = (size_t)(16 + si) * sstr + base;
  size_t d2 = (size_t)(32 + si) * sstr + base;
  if (mode == 0) { *(uint4*)&xp[d0] = H; *(uint4*)&xp[d1] = H; *(uint4*)&xp[d2] = L; }
  else           { *(uint4*)&xp[d0] = H; *(uint4*)&xp[d1] = L; *(uint4*)&xp[d2] = H; }
}

// --------------------------------------------------------- score+argmin ---
// 256x256 tile, 8 waves (2M x 4N, 128x64 each), BK=32 ring of 4 LDS slots,
// stage-ahead 3, counted vmcnt(8). m201-style dual-barrier 16-MFMA sub-phases:
// {ds_read subtile | stage issue -> barrier -> lgkm(0) -> setprio MFMA -> barrier}.
constexpr int COLT2 = 8;
constexpr int NSLICE = 384;   // 8 col-tiles x 48 slices

#define GLDS(SRC, DST) __builtin_amdgcn_global_load_lds((const unsigned int*)(SRC), (unsigned int*)(DST), 16, 0, 0)

#define SLICE(G)                                                               \
  {                                                                            \
    const int g_ = (G);                                                        \
    const char* Ab_ = (const char*)As[g_ & 3] + aoff;                          \
    const char* Bb_ = (const char*)Bs[g_ & 3] + boff;                          \
    bf16x8 af_[4], b_[4];                                                      \
    /* ---- sub-phase 0: rows 0..63 of wave tile ---- */                       \
    _Pragma("unroll")                                                          \
    for (int i_ = 0; i_ < 4; i_++) af_[i_] = *(const bf16x8*)(Ab_ + i_ * 1024);\
    _Pragma("unroll")                                                          \
    for (int j_ = 0; j_ < 4; j_++) b_[j_]  = *(const bf16x8*)(Bb_ + j_ * 1024);\
    if (g_ + 3 < NSLICE) {                                                     \
      const int sl_ = (g_ + 3) & 3;                                            \
      GLDS(zA + (size_t)sf * 2097152,        (char*)As[sl_] + t * 16);         \
      GLDS(zA + (size_t)sf * 2097152 + 8192, (char*)As[sl_] + 8192 + t * 16);  \
    }                                                                          \
    __builtin_amdgcn_s_barrier();                                              \
    asm volatile("s_waitcnt lgkmcnt(0)" ::: "memory");                         \
    __builtin_amdgcn_sched_barrier(0);                                         \
    __builtin_amdgcn_s_setprio(1);                                             \
    _Pragma("unroll")                                                          \
    for (int i_ = 0; i_ < 4; i_++)                                             \
      _Pragma("unroll")                                                        \
      for (int j_ = 0; j_ < 4; j_++)                                           \
        acc[i_][j_] = __builtin_amdgcn_mfma_f32_16x16x32_bf16(af_[i_], b_[j_], \
                                                        acc[i_][j_], 0, 0, 0); \
    __builtin_amdgcn_s_setprio(0);                                             \
    __builtin_amdgcn_s_barrier();                                              \
    __builtin_amdgcn_sched_barrier(0);                                         \
    /* ---- sub-phase 1: rows 64..127 ---- */                                  \
    _Pragma("unroll")                                                          \
    for (int i_ = 0; i_ < 4; i_++)                                             \
      af_[i_] = *(const bf16x8*)(Ab_ + 4096 + i_ * 1024);                      \
    if (g_ + 3 < NSLICE) {                                                     \
      const int sl_ = (g_ + 3) & 3;                                            \
      const size_t wOfs_ = (size_t)sf * 524288 + (size_t)ctf * 16384;          \
      GLDS(wB + wOfs_,        (char*)Bs[sl_] + t * 16);                        \
      GLDS(wB + wOfs_ + 8192, (char*)Bs[sl_] + 8192 + t * 16);                 \
      sf++; if (sf == 48) { sf = 0; ctf++; }                                   \
    }                                                                          \
    __builtin_amdgcn_s_barrier();                                              \
    asm volatile("s_waitcnt lgkmcnt(0)" ::: "memory");                         \
    __builtin_amdgcn_sched_barrier(0);                                         \
    __builtin_amdgcn_s_setprio(1);                                             \
    _Pragma("unroll")                                                          \
    for (int i_ = 0; i_ < 4; i_++)                                             \
      _Pragma("unroll")                                                        \
      for (int j_ = 0; j_ < 4; j_++)                                           \
        acc[4 + i_][j_] = __builtin_amdgcn_mfma_f32_16x16x32_bf16(af_[i_],     \
                                          b_[j_], acc[4 + i_][j_], 0, 0, 0);   \
    __builtin_amdgcn_s_setprio(0);                                             \
    if (g_ <= NSLICE - 4)      { asm volatile("s_waitcnt vmcnt(8)" ::: "memory"); } \
    else if (g_ == NSLICE - 3) { asm volatile("s_waitcnt vmcnt(4)" ::: "memory"); } \
    else if (g_ == NSLICE - 2) { asm volatile("s_waitcnt vmcnt(0)" ::: "memory"); } \
    __builtin_amdgcn_s_barrier();                                              \
    __builtin_amdgcn_sched_barrier(0);                                         \
  }

__global__ __launch_bounds__(512, 2) void score3q(
    const ushort* __restrict__ zp, const ushort* __restrict__ wp,
    const float* __restrict__ wsq, unsigned long long* __restrict__ packed) {
  __shared__ ushort As[4][8192];             // 4 slots x [256 rows][32 sh]
  __shared__ ushort Bs[4][8192];
  __shared__ float wsqs[2048];
  __shared__ unsigned long long best2[256][4];

  const int t = threadIdx.x, lane = t & 63, wid = t >> 6;
  const int wm = wid >> 2, wn = wid & 3;     // 2M x 4N wave grid
  const int l15 = lane & 15, lg = (lane >> 4) & 3;
  const int row0 = blockIdx.x * 256;
  const int cg0  = blockIdx.y * 2048;

  const char* zA = (const char*)zp + ((size_t)(row0 + (t >> 2)) * 64 + (size_t)(t & 3) * 16);
  const char* wB = (const char*)wp + ((size_t)(cg0  + (t >> 2)) * 64 + (size_t)(t & 3) * 16);

  const int swz  = (l15 >> 1) & 3;
  const int aoff = (wm * 128 + l15) * 64 + ((lg ^ swz) * 16);
  const int boff = (wn * 64  + l15) * 64 + ((lg ^ swz) * 16);

  { float4 v = *(const float4*)&wsq[cg0 + t * 4]; *(float4*)&wsqs[t * 4] = v; }
  if (t < 256) { best2[t][0] = ~0ull; best2[t][1] = ~0ull; best2[t][2] = ~0ull; best2[t][3] = ~0ull; }
  __syncthreads();                            // wsqs/best2 visible, full drain

  // prologue: stage slices 0..2 of col-tile 0 (ring slots 0..2)
  #pragma unroll
  for (int s0 = 0; s0 < 3; s0++) {
    GLDS(zA + (size_t)s0 * 2097152,        (char*)As[s0] + t * 16);
    GLDS(zA + (size_t)s0 * 2097152 + 8192, (char*)As[s0] + 8192 + t * 16);
    GLDS(wB + (size_t)s0 * 524288,         (char*)Bs[s0] + t * 16);
    GLDS(wB + (size_t)s0 * 524288 + 8192,  (char*)Bs[s0] + 8192 + t * 16);
  }
  asm volatile("s_waitcnt vmcnt(8)" ::: "memory");   // slice 0 landed (this wave)
  __builtin_amdgcn_s_barrier();                       // ...and all waves
  __builtin_amdgcn_sched_barrier(0);

  int sf = 3, ctf = 0;                        // next slice to stage

  for (int ct = 0; ct < COLT2; ct++) {
    f32x4 acc[8][4];
    #pragma unroll
    for (int i = 0; i < 8; i++)
      #pragma unroll
      for (int j = 0; j < 4; j++) acc[i][j] = (f32x4){0.f, 0.f, 0.f, 0.f};

    #pragma unroll 4
    for (int s = 0; s < 48; s++) {
      SLICE(ct * 48 + s)
    }

    // ---- epilogue: distances + argmin for this col-tile
    float rv[32]; int rx[32];
    #pragma unroll
    for (int i = 0; i < 8; i++)
      #pragma unroll
      for (int r = 0; r < 4; r++) {
        float bvv = 3.4e38f; int bii = 0;
        #pragma unroll
        for (int j = 0; j < 4; j++) {
          float wq = wsqs[ct * 256 + wn * 64 + j * 16 + l15];
          float dist = wq - 2.0f * acc[i][j][r];
          int c = cg0 + ct * 256 + wn * 64 + j * 16 + l15;
          if (dist < bvv) { bvv = dist; bii = c; }   // j ascending: first idx wins
        }
        rv[i * 4 + r] = bvv; rx[i * 4 + r] = bii;
      }
    #pragma unroll
    for (int e = 0; e < 32; e++) {
      float v = rv[e]; int ix = rx[e];
      #pragma unroll
      for (int m = 1; m < 16; m <<= 1) {
        float ov = __shfl_xor(v, m, 64);
        int   oi = __shfl_xor(ix, m, 64);
        if (ov < v || (ov == v && oi < ix)) { v = ov; ix = oi; }
      }
      rv[e] = v; rx[e] = ix;
    }
    #pragma unroll
    for (int half = 0; half < 2; half++) {     // lane l15 commits entries l15, l15+16
      const int e0 = l15 + half * 16;
      float bvv = 0.f; int bii = 0;
      #pragma unroll
      for (int e = 0; e < 32; e++) {            // static-index select (rule #20)
        bool p = (e == e0);
        bvv = p ? rv[e] : bvv; bii = p ? rx[e] : bii;
      }
      unsigned u = __float_as_uint(bvv);
      u = (u & 0x80000000u) ? ~u : (u | 0x80000000u);
      unsigned long long key = ((unsigned long long)u << 32) | (unsigned)bii;
      const int rowl = wm * 128 + (e0 >> 2) * 16 + lg * 4 + (e0 & 3);
      unsigned long long cur = best2[rowl][wn];  // single-writer slot: no atomic
      if (key < cur) best2[rowl][wn] = key;
    }
  }

  __syncthreads();
  if (t < 256) {
    unsigned long long k0 = best2[t][0], k1 = best2[t][1];
    unsigned long long k2 = best2[t][2], k3 = best2[t][3];
    unsigned long long m0 = k0 < k1 ? k0 : k1;
    unsigned long long m1 = k2 < k3 ? k2 : k3;
    atomicMin(&packed[row0 + t], m0 < m1 ? m0 : m1);
  }
}

// ---------------------------------------- fallback score (round-2 kernel) --
constexpr int LDP = 40;
constexpr int KSPLIT = 8, COLT = K_N / KSPLIT / 128;
__device__ __forceinline__ void stage16(const float* __restrict__ g,
                                        ushort* __restrict__ h,
                                        ushort* __restrict__ l) {
  float v[16];
  *(float4*)&v[0]  = *(const float4*)&g[0];
  *(float4*)&v[4]  = *(const float4*)&g[4];
  *(float4*)&v[8]  = *(const float4*)&g[8];
  *(float4*)&v[12] = *(const float4*)&g[12];
  uint hw[8], lw[8];
  #pragma unroll
  for (int i = 0; i < 8; i++) {
    uint b0 = __float_as_uint(v[2*i]);
    uint b1 = __float_as_uint(v[2*i+1]);
    float r0 = v[2*i]   - __uint_as_float(b0 & 0xFFFF0000u);
    float r1 = v[2*i+1] - __uint_as_float(b1 & 0xFFFF0000u);
    hw[i] = (b0 >> 16) | (b1 & 0xFFFF0000u);
    lw[i] = (__float_as_uint(r0) >> 16) | (__float_as_uint(r1) & 0xFFFF0000u);
  }
  ((uint4*)h)[0] = *(uint4*)&hw[0];
  ((uint4*)h)[1] = *(uint4*)&hw[4];
  ((uint4*)l)[0] = *(uint4*)&lw[0];
  ((uint4*)l)[1] = *(uint4*)&lw[4];
}

__global__ __launch_bounds__(256, 2) void score_argmin_mfma(
    const float* __restrict__ z, const float* __restrict__ w,
    const float* __restrict__ wsq, unsigned long long* __restrict__ packed) {
  __shared__ ushort Ah[128][LDP];
  __shared__ ushort Al[128][LDP];
  __shared__ ushort Bh[128][LDP];
  __shared__ ushort Bl[128][LDP];
  const int t = threadIdx.x, lane = t & 63, wid = t >> 6;
  const int wm = wid >> 1, wn = wid & 1;
  const int l15 = lane & 15, lg = lane >> 4;
  const int row0 = blockIdx.x * 128;
  const int ks0  = blockIdx.y * (K_N / KSPLIT);
  const int srow = t >> 1, skq = (t & 1) * 16;
  float rmin[16]; int ridx[16];
  #pragma unroll
  for (int e = 0; e < 16; e++) { rmin[e] = 3.4e38f; ridx[e] = 0; }
  for (int ct = 0; ct < COLT; ct++) {
    const int c0 = ks0 + ct * 128;
    f32x4 acc[4][4];
    #pragma unroll
    for (int i = 0; i < 4; i++)
      #pragma unroll
      for (int j = 0; j < 4; j++) acc[i][j] = (f32x4){0.f, 0.f, 0.f, 0.f};
    for (int k0 = 0; k0 < D_N; k0 += 32) {
      __syncthreads();
      stage16(&z[(size_t)(row0 + srow) * D_N + k0 + skq], &Ah[srow][skq], &Al[srow][skq]);
      stage16(&w[(size_t)(c0   + srow) * D_N + k0 + skq], &Bh[srow][skq], &Bl[srow][skq]);
      __syncthreads();
      bf16x8 ah[4], al[4], bh[4], bl[4];
      #pragma unroll
      for (int i = 0; i < 4; i++) {
        ah[i] = *(const bf16x8*)&Ah[wm*64 + i*16 + l15][lg*8];
        al[i] = *(const bf16x8*)&Al[wm*64 + i*16 + l15][lg*8];
        bh[i] = *(const bf16x8*)&Bh[wn*64 + i*16 + l15][lg*8];
        bl[i] = *(const bf16x8*)&Bl[wn*64 + i*16 + l15][lg*8];
      }
      #pragma unroll
      for (int i = 0; i < 4; i++)
        #pragma unroll
        for (int j = 0; j < 4; j++) {
          acc[i][j] = __builtin_amdgcn_mfma_f32_16x16x32_bf16(ah[i], bh[j], acc[i][j], 0, 0, 0);
          acc[i][j] = __builtin_amdgcn_mfma_f32_16x16x32_bf16(ah[i], bl[j], acc[i][j], 0, 0, 0);
          acc[i][j] = __builtin_amdgcn_mfma_f32_16x16x32_bf16(al[i], bh[j], acc[i][j], 0, 0, 0);
        }
    }
    float wq[4];
    #pragma unroll
    for (int j = 0; j < 4; j++) wq[j] = wsq[c0 + wn*64 + j*16 + l15];
    #pragma unroll
    for (int i = 0; i < 4; i++)
      #pragma unroll
      for (int r = 0; r < 4; r++) {
        const int e = i * 4 + r;
        #pragma unroll
        for (int j = 0; j < 4; j++) {
          float dist = wq[j] - 2.0f * acc[i][j][r];
          if (dist < rmin[e]) { rmin[e] = dist; ridx[e] = c0 + wn*64 + j*16 + l15; }
        }
      }
  }
  #pragma unroll
  for (int e = 0; e < 16; e++) {
    float v = rmin[e]; int ix = ridx[e];
    #pragma unroll
    for (int m = 1; m < 16; m <<= 1) {
      float ov = __shfl_xor(v, m, 64);
      int   oi = __shfl_xor(ix, m, 64);
      if (ov < v || (ov == v && oi < ix)) { v = ov; ix = oi; }
    }
    rmin[e] = v; ridx[e] = ix;
  }
  const int s = l15;
  float bv = 0.f; int bi = 0;
  #pragma unroll
  for (int e = 0; e < 16; e++) {
    bool p = (e == s);
    bv = p ? rmin[e] : bv;
    bi = p ? ridx[e] : bi;
  }
  unsigned u = __float_as_uint(bv);
  u = (u & 0x80000000u) ? ~u : (u | 0x80000000u);
  unsigned long long key = ((unsigned long long)u << 32) | (unsigned)bi;
  atomicMin(&packed[row0 + wm*64 + (s >> 2)*16 + lg*4 + (s & 3)], key);
}

// ------------------------------------------- counting-sort segment-sum ----
__global__ __launch_bounds__(256) void count_kernel(
    const unsigned long long* __restrict__ packed, int* __restrict__ cnt,
    float* __restrict__ idxout) {
  int row = blockIdx.x * 256 + threadIdx.x;
  int idx = (int)(packed[row] & 0xFFFFFFFFull);
  idxout[row] = (float)idx;
  atomicAdd(&cnt[idx], 1);
}

__global__ __launch_bounds__(256) void scan_kernel(const int* __restrict__ cnt,
                                                   int* __restrict__ offs,
                                                   int* __restrict__ cursor) {
  int t = threadIdx.x;
  int base = t * 32;
  int local[32];
  int s = 0;
  #pragma unroll
  for (int i = 0; i < 32; i++) { local[i] = s; s += cnt[base + i]; }
  __shared__ int ps[257];
  ps[t + 1] = s;
  if (t == 0) ps[0] = 0;
  __syncthreads();
  if (t == 0) { for (int i = 1; i <= 256; i++) ps[i] += ps[i - 1]; }
  __syncthreads();
  int e = ps[t];
  #pragma unroll
  for (int i = 0; i < 32; i++) {
    int o = e + local[i];
    offs[base + i] = o; cursor[base + i] = o;
  }
  if (t == 255) offs[8192] = ps[256];
}

__global__ __launch_bounds__(256) void scatter_ids(
    const unsigned long long* __restrict__ packed, int* __restrict__ cursor,
    int* __restrict__ rowlist) {
  int row = blockIdx.x * 256 + threadIdx.x;
  int idx = (int)(packed[row] & 0xFFFFFFFFull);
  int pos = atomicAdd(&cursor[idx], 1);
  rowlist[pos] = row;
}

__global__ __launch_bounds__(256) void seg_accum(
    const float* __restrict__ z, const float* __restrict__ edw,
    const float* __restrict__ ecs, const int* __restrict__ offs,
    const int* __restrict__ rowlist, float* __restrict__ nedw_out,
    float* __restrict__ ncs_out) {
  int k = blockIdx.x, t = threadIdx.x;
  int s0 = offs[k], s1 = offs[k + 1];
  float ax = 0.f, ay = 0.f;
  for (int r = s0; r < s1; r++) {
    int row = rowlist[r];
    float2 zv = *(const float2*)&z[(size_t)row * D_N + t * 2];
    ax += zv.x; ay += zv.y;
  }
  float2 ev = *(const float2*)&edw[(size_t)k * D_N + t * 2];
  float2 o;
  o.x = EMA * ev.x + ONE_M_EMA * ax;
  o.y = EMA * ev.y + ONE_M_EMA * ay;
  *(float2*)&nedw_out[(size_t)k * D_N + t * 2] = o;
  if (t == 0) ncs_out[k] = EMA * ecs[k] + ONE_M_EMA * (float)(s1 - s0);
}

// ------------------------------------------------ quantize + loss partial --
__global__ __launch_bounds__(256) void quant_loss(
    const float* __restrict__ z, const float* __restrict__ w,
    const unsigned long long* __restrict__ packed,
    float* __restrict__ qout, float* __restrict__ lpart) {
  int row = blockIdx.x, t = threadIdx.x;
  int idx = (int)(packed[row] & 0xFFFFFFFFull);
  float2 zv = *(const float2*)&z[(size_t)row * D_N + t * 2];
  float2 wv = *(const float2*)&w[(size_t)idx * D_N + t * 2];
  float2 q;
  q.x = zv.x + (wv.x - zv.x);
  q.y = zv.y + (wv.y - zv.y);
  *(float2*)&qout[(size_t)row * D_N + t * 2] = q;
  float dx = zv.x - wv.x, dy = zv.y - wv.y;
  float s = dx * dx + dy * dy;
  #pragma unroll
  for (int off = 32; off; off >>= 1) s += __shfl_down(s, off);
  __shared__ float part[4];
  if ((t & 63) == 0) part[t >> 6] = s;
  __syncthreads();
  if (t == 0) lpart[row] = part[0] + part[1] + part[2] + part[3];
}

// ------------------------------------------------------------- reductions -
__global__ __launch_bounds__(256) void reduce2(const float* __restrict__ ncs_out,
                                               const float* __restrict__ lpart,
                                               float* __restrict__ nsum,
                                               float* __restrict__ loss_sum) {
  int t = threadIdx.x;
  float s1 = 0.f, s2 = 0.f;
  for (int i = t; i < K_N; i += 256) s1 += ncs_out[i];
  for (int i = t; i < B_N; i += 256) s2 += lpart[i];
  #pragma unroll
  for (int off = 32; off; off >>= 1) {
    s1 += __shfl_down(s1, off);
    s2 += __shfl_down(s2, off);
  }
  __shared__ float p1[4], p2[4];
  if ((t & 63) == 0) { p1[t >> 6] = s1; p2[t >> 6] = s2; }
  __syncthreads();
  if (t == 0) {
    nsum[0]     = p1[0] + p1[1] + p1[2] + p1[3];
    loss_sum[0] = p2[0] + p2[1] + p2[2] + p2[3];
  }
}

// fallback-path kernels
__global__ __launch_bounds__(256) void gather_scatter(
    const float* __restrict__ z, const float* __restrict__ w,
    const unsigned long long* __restrict__ packed,
    float* __restrict__ qout, float* __restrict__ idxout,
    float* __restrict__ ncs_out, float* __restrict__ nedw_out,
    float* __restrict__ loss_sum) {
  int row = blockIdx.x;
  int t   = threadIdx.x;
  int idx = (int)(packed[row] & 0xFFFFFFFFull);
  float2 zv = *(const float2*)&z[(size_t)row * D_N + t * 2];
  float2 wv = *(const float2*)&w[(size_t)idx * D_N + t * 2];
  float2 q;
  q.x = zv.x + (wv.x - zv.x);
  q.y = zv.y + (wv.y - zv.y);
  *(float2*)&qout[(size_t)row * D_N + t * 2] = q;
  float dx = zv.x - wv.x, dy = zv.y - wv.y;
  float s = dx*dx + dy*dy;
  #pragma unroll
  for (int off = 32; off; off >>= 1) s += __shfl_down(s, off);
  __shared__ float part[4];
  if ((t & 63) == 0) part[t >> 6] = s;
  __syncthreads();
  if (t == 0) {
    atomicAdd(loss_sum, part[0] + part[1] + part[2] + part[3]);
    atomicAdd(&ncs_out[idx], ONE_M_EMA);
    idxout[row] = (float)idx;
  }
  atomicAdd(&nedw_out[(size_t)idx * D_N + t*2],     ONE_M_EMA * zv.x);
  atomicAdd(&nedw_out[(size_t)idx * D_N + t*2 + 1], ONE_M_EMA * zv.y);
}

__global__ __launch_bounds__(256) void reduce_n(const float* __restrict__ ncs_out,
                                                float* __restrict__ nsum) {
  int t = threadIdx.x;
  float s = 0.f;
  for (int i = t; i < K_N; i += 256) s += ncs_out[i];
  #pragma unroll
  for (int off = 32; off; off >>= 1) s += __shfl_down(s, off);
  __shared__ float part[4];
  if ((t & 63) == 0) part[t >> 6] = s;
  __syncthreads();
  if (t == 0) nsum[0] = part[0] + part[1] + part[2] + part[3];
}

__global__ __launch_bounds__(256) void finalize(
    const float* __restrict__ ncs_out, const float* __restrict__ nedw_out,
    float* __restrict__ nw_out, const float* __restrict__ nsum,
    const float* __restrict__ loss_sum, float* __restrict__ loss_out) {
  size_t i = (size_t)blockIdx.x * 256 + threadIdx.x;
  float n = nsum[0];
  int k = (int)(i >> 9);
  float nv = ncs_out[k];
  float cs = (nv + EPS_) / (n + K_N * EPS_) * n;
  nw_out[i] = nedw_out[i] / cs;
  if (i == 0) loss_out[0] = CCOST * loss_sum[0] / (float)((size_t)B_N * D_N);
}

// ------------------------------------------------------------------ launch -
extern "C" void kernel_launch(void* const* d_in, const int* in_sizes, int n_in,
                              void* d_out, int out_size, void* d_ws, size_t ws_size,
                              hipStream_t stream) {
  const float* z   = (const float*)d_in[0];
  const float* w   = (const float*)d_in[1];
  const float* ecs = (const float*)d_in[2];
  const float* edw = (const float*)d_in[3];

  float* out      = (float*)d_out;
  float* qout     = out;
  float* idxout   = out + (size_t)B_N * D_N;
  float* loss_out = idxout + B_N;
  float* nw_out   = loss_out + 1;
  float* ncs_out  = nw_out + (size_t)K_N * D_N;
  float* nedw_out = ncs_out + K_N;

  unsigned long long* packed = (unsigned long long*)d_ws;
  float* wsq      = (float*)((char*)d_ws + 262144);
  float* loss_sum = (float*)((char*)d_ws + 294912);
  float* nsum     = loss_sum + 1;

  hipMemsetAsync(d_ws, 0xFF, 262144, stream);
  hipMemsetAsync((void*)loss_sum, 0, 8, stream);

  prep_kernel<<<2048, 256, 0, stream>>>(w, ecs, wsq, ncs_out);

  if (ws_size >= WS_NEED) {
    ushort* zp  = (ushort*)((char*)d_ws + ZP_OFF);
    ushort* wp  = (ushort*)((char*)d_ws + WP_OFF);
    int* cnt    = (int*)((char*)d_ws + CNT_OFF);
    int* offs   = (int*)((char*)d_ws + OFFS_OFF);
    int* cursor = (int*)((char*)d_ws + CURS_OFF);
    int* rowl   = (int*)((char*)d_ws + ROWL_OFF);
    float* lpart= (float*)((char*)d_ws + LPART_OFF);

    split_pack<<<8192, 256, 0, stream>>>(z, zp, B_N, 0);
    split_pack<<<2048, 256, 0, stream>>>(w, wp, K_N, 1);
    score3q<<<dim3(128, 4), 512, 0, stream>>>(zp, wp, wsq, packed);
    // aux arrays alias zp (dead after score3q) -> init only now
    hipMemsetAsync((void*)cnt, 0, K_N * sizeof(int), stream);
    count_kernel<<<B_N / 256, 256, 0, stream>>>(packed, cnt, idxout);
    scan_kernel<<<1, 256, 0, stream>>>(cnt, offs, cursor);
    scatter_ids<<<B_N / 256, 256, 0, stream>>>(packed, cursor, rowl);
    seg_accum<<<K_N, 256, 0, stream>>>(z, edw, ecs, offs, rowl, nedw_out, ncs_out);
    quant_loss<<<B_N, 256, 0, stream>>>(z, w, packed, qout, lpart);
    reduce2<<<1, 256, 0, stream>>>(ncs_out, lpart, nsum, loss_sum);
  } else {
    prep_nedw<<<4096, 256, 0, stream>>>((const float4*)edw, (float4*)nedw_out);
    score_argmin_mfma<<<dim3(B_N / 128, KSPLIT), 256, 0, stream>>>(z, w, wsq, packed);
    gather_scatter<<<B_N, 256, 0, stream>>>(z, w, packed, qout, idxout,
                                            ncs_out, nedw_out, loss_sum);
    reduce_n<<<1, 256, 0, stream>>>(ncs_out, nsum);
  }

  finalize<<<K_N * D_N / 256, 256, 0, stream>>>(ncs_out, nedw_out, nw_out,
                                                nsum, loss_sum, loss_out);
}

// Round 10
// 1023.181 us; speedup vs baseline: 2.0334x; 1.0776x over previous
//
#include <hip/hip_runtime.h>

#define B_N 32768
#define D_N 512
#define K_N 8192
#define EMA 0.99f
#define ONE_M_EMA 0.01f
#define EPS_ 1e-5f
#define CCOST 0.25f

// ws layout (fast path):
// [0, 262144)            : u64 packed[B_N]  (low32 = idx), init 0xFF
// [262144, 294912)       : float wsq[K_N]
// [294912, 294920)       : float loss_sum, n_sum
// [295936, +67108864)    : ushort zp[32][32768][32]  {hi:0-15, lo:16-31}, chunk-XOR swizzled
// [67404800, +16777216)  : ushort wp[32][8192][32]   {hi:0-15, lo:16-31}
// Logical K' = 1536 = 48 slices; z sections [hi|hi|lo], w sections [hi|lo|hi]
// are realized by slice->physical mapping at stage time (dedup saves 41MB writes).
#define ZP_OFF 295936ull
#define WP_OFF 67404800ull
#define WS_NEED (WP_OFF + 16777216ull)
#define CNT_OFF    295936ull
#define OFFS_OFF   332800ull
#define CURS_OFF   365568ull
#define ROWL_OFF   398336ull
#define LPART_OFF  529408ull

typedef __attribute__((ext_vector_type(8))) short bf16x8;
typedef __attribute__((ext_vector_type(4))) float f32x4;

// ---------------------------------------------------------------- prep ----
// (fallback path only; fast path gets wsq from split_w)
__global__ __launch_bounds__(256) void prep_kernel(const float* __restrict__ w,
                                                   const float* __restrict__ ecs,
                                                   float* __restrict__ wsq,
                                                   float* __restrict__ ncs_out) {
  int row  = blockIdx.x * 4 + (threadIdx.x >> 6);
  int lane = threadIdx.x & 63;
  const float* p = w + (size_t)row * D_N + lane * 8;
  float4 a = *(const float4*)p;
  float4 b = *(const float4*)(p + 4);
  float s = a.x*a.x + a.y*a.y + a.z*a.z + a.w*a.w
          + b.x*b.x + b.y*b.y + b.z*b.z + b.w*b.w;
  #pragma unroll
  for (int off = 32; off; off >>= 1) s += __shfl_down(s, off);
  if (lane == 0) wsq[row] = s;

  int gid = blockIdx.x * 256 + threadIdx.x;
  if (gid < K_N) ncs_out[gid] = EMA * ecs[gid];
}

__global__ __launch_bounds__(256) void prep_nedw(const float4* __restrict__ edw,
                                                 float4* __restrict__ nedw) {
  int i = blockIdx.x * 256 + threadIdx.x;
  float4 v = edw[i];
  v.x *= EMA; v.y *= EMA; v.z *= EMA; v.w *= EMA;
  nedw[i] = v;
}

// ------------------------------------------------------------ pre-split ---
// x[R][512] f32 -> xp[32][R][32] bf16: physical sec0 = hi slices, sec1 = lo.
// 16B chunk stored at (c ^ ((row>>1)&3)) -- ds_read-side XOR swizzle baked in.
__global__ __launch_bounds__(256) void split_z(const float* __restrict__ x,
                                               ushort* __restrict__ xp) {
  int g   = blockIdx.x * 256 + threadIdx.x;
  int row = g >> 6, c = g & 63;
  const float* src = x + (size_t)row * 512 + c * 8;
  float v[8];
  *(float4*)&v[0] = *(const float4*)&src[0];
  *(float4*)&v[4] = *(const float4*)&src[4];
  uint hw[4], lw[4];
  #pragma unroll
  for (int i = 0; i < 4; i++) {
    uint b0 = __float_as_uint(v[2*i]);
    uint b1 = __float_as_uint(v[2*i+1]);
    float r0 = v[2*i]   - __uint_as_float(b0 & 0xFFFF0000u);
    float r1 = v[2*i+1] - __uint_as_float(b1 & 0xFFFF0000u);
    hw[i] = (b0 >> 16) | (b1 & 0xFFFF0000u);
    lw[i] = (__float_as_uint(r0) >> 16) | (__float_as_uint(r1) & 0xFFFF0000u);
  }
  int si  = c >> 2;
  int p   = (c & 3) ^ ((row >> 1) & 3);
  size_t sstr = (size_t)B_N * 32;
  size_t base = (size_t)row * 32 + (size_t)p * 8;
  *(uint4*)&xp[(size_t)si * sstr + base]        = (uint4){hw[0], hw[1], hw[2], hw[3]};
  *(uint4*)&xp[(size_t)(16 + si) * sstr + base] = (uint4){lw[0], lw[1], lw[2], lw[3]};
}

// split_w also computes wsq (fuses prep's w pass; one wave per row)
__global__ __launch_bounds__(256) void split_w(const float* __restrict__ x,
                                               ushort* __restrict__ xp,
                                               float* __restrict__ wsq) {
  int g   = blockIdx.x * 256 + threadIdx.x;
  int row = g >> 6, c = g & 63;
  const float* src = x + (size_t)row * 512 + c * 8;
  float v[8];
  *(float4*)&v[0] = *(const float4*)&src[0];
  *(float4*)&v[4] = *(const float4*)&src[4];
  uint hw[4], lw[4]; float w2 = 0.f;
  #pragma unroll
  for (int i = 0; i < 4; i++) {
    uint b0 = __float_as_uint(v[2*i]);
    uint b1 = __float_as_uint(v[2*i+1]);
    float r0 = v[2*i]   - __uint_as_float(b0 & 0xFFFF0000u);
    float r1 = v[2*i+1] - __uint_as_float(b1 & 0xFFFF0000u);
    hw[i] = (b0 >> 16) | (b1 & 0xFFFF0000u);
    lw[i] = (__float_as_uint(r0) >> 16) | (__float_as_uint(r1) & 0xFFFF0000u);
    w2 += v[2*i]*v[2*i] + v[2*i+1]*v[2*i+1];
  }
  int si  = c >> 2;
  int p   = (c & 3) ^ ((row >> 1) & 3);
  size_t sstr = (size_t)K_N * 32;
  size_t base = (size_t)row * 32 + (size_t)p * 8;
  *(uint4*)&xp[(size_t)si * sstr + base]        = (uint4){hw[0], hw[1], hw[2], hw[3]};
  *(uint4*)&xp[(size_t)(16 + si) * sstr + base] = (uint4){lw[0], lw[1], lw[2], lw[3]};
  #pragma unroll
  for (int off = 32; off; off >>= 1) w2 += __shfl_down(w2, off);
  if (c == 0) wsq[row] = w2;
}

// --------------------------------------------------------- score+argmin ---
// 256x256 tile, 8 waves (2M x 4N, 128x64 each), BK=32 ring of 4 LDS slots,
// fragment E/O double-buffer (round-6 structure): MFMA never waits on lgkm;
// counted vmcnt(8). Logical slice sf in [0,48): z = [hi|hi|lo], w = [hi|lo|hi]
// realized via slice->physical maps zsl/wsl (dedup'd storage).
constexpr int COLT2 = 8;

#define GLDS(SRC, DST) __builtin_amdgcn_global_load_lds((const unsigned int*)(SRC), (unsigned int*)(DST), 16, 0, 0)

#define PHASE(AC, BC, AL, BL, G)                                               \
  {                                                                            \
    const int g_ = (G);                                                        \
    if (g_ + 1 <= 383) {                                                       \
      const char* Ab_ = (const char*)As[(g_ + 1) & 3] + aoff;                  \
      const char* Bb_ = (const char*)Bs[(g_ + 1) & 3] + boff;                  \
      _Pragma("unroll")                                                        \
      for (int i_ = 0; i_ < 8; i_++) AL[i_] = *(const bf16x8*)(Ab_ + i_ * 1024);\
      _Pragma("unroll")                                                        \
      for (int j_ = 0; j_ < 4; j_++) BL[j_] = *(const bf16x8*)(Bb_ + j_ * 1024);\
    }                                                                          \
    if (g_ + 4 <= 383) {                                                       \
      const int slotF_ = sf & 3;                                               \
      const int zsl_ = (sf < 32) ? (sf & 15) : (sf - 16);  /* [hi|hi|lo] */    \
      const int wsl_ = (sf < 32) ? sf : (sf - 32);         /* [hi|lo|hi] */    \
      GLDS(zA + (size_t)zsl_ * 2097152,        (char*)As[slotF_] + t * 16);    \
      GLDS(zA + (size_t)zsl_ * 2097152 + 8192, (char*)As[slotF_] + 8192 + t * 16);\
      const size_t wOfs_ = (size_t)wsl_ * 524288 + (size_t)ctf * 16384;        \
      GLDS(wB + wOfs_,        (char*)Bs[slotF_] + t * 16);                     \
      GLDS(wB + wOfs_ + 8192, (char*)Bs[slotF_] + 8192 + t * 16);              \
      sf++; if (sf == 48) { sf = 0; ctf++; }                                   \
    }                                                                          \
    __builtin_amdgcn_s_setprio(1);                                             \
    _Pragma("unroll")                                                          \
    for (int i_ = 0; i_ < 8; i_++)                                             \
      _Pragma("unroll")                                                        \
      for (int j_ = 0; j_ < 4; j_++)                                           \
        acc[i_][j_] = __builtin_amdgcn_mfma_f32_16x16x32_bf16(AC[i_], BC[j_],  \
                                                        acc[i_][j_], 0, 0, 0); \
    __builtin_amdgcn_s_setprio(0);                                             \
    asm volatile("s_waitcnt lgkmcnt(0)" ::: "memory");                         \
    if (g_ <= 379)      { asm volatile("s_waitcnt vmcnt(8)" ::: "memory"); }   \
    else if (g_ == 380) { asm volatile("s_waitcnt vmcnt(4)" ::: "memory"); }   \
    else if (g_ == 381) { asm volatile("s_waitcnt vmcnt(0)" ::: "memory"); }   \
    __builtin_amdgcn_s_barrier();                                              \
    __builtin_amdgcn_sched_barrier(0);                                         \
  }

__global__ __launch_bounds__(512, 2) void score3p(
    const ushort* __restrict__ zp, const ushort* __restrict__ wp,
    const float* __restrict__ wsq, unsigned long long* __restrict__ packed) {
  __shared__ ushort As[4][8192];             // 4 slots x [256 rows][32 sh]
  __shared__ ushort Bs[4][8192];
  __shared__ float wsqs[2048];
  __shared__ unsigned long long best2[256][4];

  const int t = threadIdx.x, lane = t & 63, wid = t >> 6;
  const int wm = wid >> 2, wn = wid & 3;     // 2M x 4N wave grid
  const int l15 = lane & 15, lg = (lane >> 4) & 3;
  const int row0 = blockIdx.x * 256;
  const int cg0  = blockIdx.y * 2048;

  const char* zA = (const char*)zp + ((size_t)(row0 + (t >> 2)) * 64 + (size_t)(t & 3) * 16);
  const char* wB = (const char*)wp + ((size_t)(cg0  + (t >> 2)) * 64 + (size_t)(t & 3) * 16);

  const int swz  = (l15 >> 1) & 3;
  const int aoff = (wm * 128 + l15) * 64 + ((lg ^ swz) * 16);
  const int boff = (wn * 64  + l15) * 64 + ((lg ^ swz) * 16);

  { float4 v = *(const float4*)&wsq[cg0 + t * 4]; *(float4*)&wsqs[t * 4] = v; }
  if (t < 256) { best2[t][0] = ~0ull; best2[t][1] = ~0ull; best2[t][2] = ~0ull; best2[t][3] = ~0ull; }
  __syncthreads();                            // wsqs/best2 visible, full drain

  // prologue: stage slices 0..3 of col-tile 0 (identity slice mapping: sf<16)
  #pragma unroll
  for (int s0 = 0; s0 < 4; s0++) {
    GLDS(zA + (size_t)s0 * 2097152,        (char*)As[s0] + t * 16);
    GLDS(zA + (size_t)s0 * 2097152 + 8192, (char*)As[s0] + 8192 + t * 16);
    GLDS(wB + (size_t)s0 * 524288,         (char*)Bs[s0] + t * 16);
    GLDS(wB + (size_t)s0 * 524288 + 8192,  (char*)Bs[s0] + 8192 + t * 16);
  }
  asm volatile("s_waitcnt vmcnt(8)" ::: "memory");   // slices 0,1 landed (this wave)
  __builtin_amdgcn_s_barrier();                       // ...and all waves
  __builtin_amdgcn_sched_barrier(0);

  bf16x8 aE[8], bE[4], aO[8], bO[4];
  #pragma unroll
  for (int i = 0; i < 8; i++) aE[i] = *(const bf16x8*)((const char*)As[0] + aoff + i * 1024);
  #pragma unroll
  for (int j = 0; j < 4; j++) bE[j] = *(const bf16x8*)((const char*)Bs[0] + boff + j * 1024);
  asm volatile("s_waitcnt lgkmcnt(0)" ::: "memory");  // frags(0) drained
  __builtin_amdgcn_s_barrier();                       // ...in all waves
  __builtin_amdgcn_sched_barrier(0);

  int sf = 4, ctf = 0;                        // next slice to stage

  for (int ct = 0; ct < COLT2; ct++) {
    f32x4 acc[8][4];
    #pragma unroll
    for (int i = 0; i < 8; i++)
      #pragma unroll
      for (int j = 0; j < 4; j++) acc[i][j] = (f32x4){0.f, 0.f, 0.f, 0.f};

    for (int s = 0; s < 48; s += 2) {
      const int g = ct * 48 + s;
      PHASE(aE, bE, aO, bO, g)                // even: compute E, load O=frags(g+1)
      PHASE(aO, bO, aE, bE, g + 1)            // odd:  compute O, load E=frags(g+2)
    }

    // ---- epilogue: distances + argmin for this col-tile
    float rv[32]; int rx[32];
    #pragma unroll
    for (int i = 0; i < 8; i++)
      #pragma unroll
      for (int r = 0; r < 4; r++) {
        float bvv = 3.4e38f; int bii = 0;
        #pragma unroll
        for (int j = 0; j < 4; j++) {
          float wq = wsqs[ct * 256 + wn * 64 + j * 16 + l15];
          float dist = wq - 2.0f * acc[i][j][r];
          int c = cg0 + ct * 256 + wn * 64 + j * 16 + l15;
          if (dist < bvv) { bvv = dist; bii = c; }   // j ascending: first idx wins
        }
        rv[i * 4 + r] = bvv; rx[i * 4 + r] = bii;
      }
    #pragma unroll
    for (int e = 0; e < 32; e++) {
      float v = rv[e]; int ix = rx[e];
      #pragma unroll
      for (int m = 1; m < 16; m <<= 1) {
        float ov = __shfl_xor(v, m, 64);
        int   oi = __shfl_xor(ix, m, 64);
        if (ov < v || (ov == v && oi < ix)) { v = ov; ix = oi; }
      }
      rv[e] = v; rx[e] = ix;
    }
    #pragma unroll
    for (int half = 0; half < 2; half++) {     // lane l15 commits entries l15, l15+16
      const int e0 = l15 + half * 16;
      float bvv = 0.f; int bii = 0;
      #pragma unroll
      for (int e = 0; e < 32; e++) {            // static-index select (rule #20)
        bool p = (e == e0);
        bvv = p ? rv[e] : bvv; bii = p ? rx[e] : bii;
      }
      unsigned u = __float_as_uint(bvv);
      u = (u & 0x80000000u) ? ~u : (u | 0x80000000u);
      unsigned long long key = ((unsigned long long)u << 32) | (unsigned)bii;
      const int rowl = wm * 128 + (e0 >> 2) * 16 + lg * 4 + (e0 & 3);
      unsigned long long cur = best2[rowl][wn];  // single-writer slot: no atomic
      if (key < cur) best2[rowl][wn] = key;
    }
  }

  __syncthreads();
  if (t < 256) {
    unsigned long long k0 = best2[t][0], k1 = best2[t][1];
    unsigned long long k2 = best2[t][2], k3 = best2[t][3];
    unsigned long long m0 = k0 < k1 ? k0 : k1;
    unsigned long long m1 = k2 < k3 ? k2 : k3;
    atomicMin(&packed[row0 + t], m0 < m1 ? m0 : m1);
  }
}

// ---------------------------------------- fallback score (round-2 kernel) --
constexpr int LDP = 40;
constexpr int KSPLIT = 8, COLT = K_N / KSPLIT / 128;
__device__ __forceinline__ void stage16(const float* __restrict__ g,
                                        ushort* __restrict__ h,
                                        ushort* __restrict__ l) {
  float v[16];
  *(float4*)&v[0]  = *(const float4*)&g[0];
  *(float4*)&v[4]  = *(const float4*)&g[4];
  *(float4*)&v[8]  = *(const float4*)&g[8];
  *(float4*)&v[12] = *(const float4*)&g[12];
  uint hw[8], lw[8];
  #pragma unroll
  for (int i = 0; i < 8; i++) {
    uint b0 = __float_as_uint(v[2*i]);
    uint b1 = __float_as_uint(v[2*i+1]);
    float r0 = v[2*i]   - __uint_as_float(b0 & 0xFFFF0000u);
    float r1 = v[2*i+1] - __uint_as_float(b1 & 0xFFFF0000u);
    hw[i] = (b0 >> 16) | (b1 & 0xFFFF0000u);
    lw[i] = (__float_as_uint(r0) >> 16) | (__float_as_uint(r1) & 0xFFFF0000u);
  }
  ((uint4*)h)[0] = *(uint4*)&hw[0];
  ((uint4*)h)[1] = *(uint4*)&hw[4];
  ((uint4*)l)[0] = *(uint4*)&lw[0];
  ((uint4*)l)[1] = *(uint4*)&lw[4];
}

__global__ __launch_bounds__(256, 2) void score_argmin_mfma(
    const float* __restrict__ z, const float* __restrict__ w,
    const float* __restrict__ wsq, unsigned long long* __restrict__ packed) {
  __shared__ ushort Ah[128][LDP];
  __shared__ ushort Al[128][LDP];
  __shared__ ushort Bh[128][LDP];
  __shared__ ushort Bl[128][LDP];
  const int t = threadIdx.x, lane = t & 63, wid = t >> 6;
  const int wm = wid >> 1, wn = wid & 1;
  const int l15 = lane & 15, lg = lane >> 4;
  const int row0 = blockIdx.x * 128;
  const int ks0  = blockIdx.y * (K_N / KSPLIT);
  const int srow = t >> 1, skq = (t & 1) * 16;
  float rmin[16]; int ridx[16];
  #pragma unroll
  for (int e = 0; e < 16; e++) { rmin[e] = 3.4e38f; ridx[e] = 0; }
  for (int ct = 0; ct < COLT; ct++) {
    const int c0 = ks0 + ct * 128;
    f32x4 acc[4][4];
    #pragma unroll
    for (int i = 0; i < 4; i++)
      #pragma unroll
      for (int j = 0; j < 4; j++) acc[i][j] = (f32x4){0.f, 0.f, 0.f, 0.f};
    for (int k0 = 0; k0 < D_N; k0 += 32) {
      __syncthreads();
      stage16(&z[(size_t)(row0 + srow) * D_N + k0 + skq], &Ah[srow][skq], &Al[srow][skq]);
      stage16(&w[(size_t)(c0   + srow) * D_N + k0 + skq], &Bh[srow][skq], &Bl[srow][skq]);
      __syncthreads();
      bf16x8 ah[4], al[4], bh[4], bl[4];
      #pragma unroll
      for (int i = 0; i < 4; i++) {
        ah[i] = *(const bf16x8*)&Ah[wm*64 + i*16 + l15][lg*8];
        al[i] = *(const bf16x8*)&Al[wm*64 + i*16 + l15][lg*8];
        bh[i] = *(const bf16x8*)&Bh[wn*64 + i*16 + l15][lg*8];
        bl[i] = *(const bf16x8*)&Bl[wn*64 + i*16 + l15][lg*8];
      }
      #pragma unroll
      for (int i = 0; i < 4; i++)
        #pragma unroll
        for (int j = 0; j < 4; j++) {
          acc[i][j] = __builtin_amdgcn_mfma_f32_16x16x32_bf16(ah[i], bh[j], acc[i][j], 0, 0, 0);
          acc[i][j] = __builtin_amdgcn_mfma_f32_16x16x32_bf16(ah[i], bl[j], acc[i][j], 0, 0, 0);
          acc[i][j] = __builtin_amdgcn_mfma_f32_16x16x32_bf16(al[i], bh[j], acc[i][j], 0, 0, 0);
        }
    }
    float wq[4];
    #pragma unroll
    for (int j = 0; j < 4; j++) wq[j] = wsq[c0 + wn*64 + j*16 + l15];
    #pragma unroll
    for (int i = 0; i < 4; i++)
      #pragma unroll
      for (int r = 0; r < 4; r++) {
        const int e = i * 4 + r;
        #pragma unroll
        for (int j = 0; j < 4; j++) {
          float dist = wq[j] - 2.0f * acc[i][j][r];
          if (dist < rmin[e]) { rmin[e] = dist; ridx[e] = c0 + wn*64 + j*16 + l15; }
        }
      }
  }
  #pragma unroll
  for (int e = 0; e < 16; e++) {
    float v = rmin[e]; int ix = ridx[e];
    #pragma unroll
    for (int m = 1; m < 16; m <<= 1) {
      float ov = __shfl_xor(v, m, 64);
      int   oi = __shfl_xor(ix, m, 64);
      if (ov < v || (ov == v && oi < ix)) { v = ov; ix = oi; }
    }
    rmin[e] = v; ridx[e] = ix;
  }
  const int s = l15;
  float bv = 0.f; int bi = 0;
  #pragma unroll
  for (int e = 0; e < 16; e++) {
    bool p = (e == s);
    bv = p ? rmin[e] : bv;
    bi = p ? ridx[e] : bi;
  }
  unsigned u = __float_as_uint(bv);
  u = (u & 0x80000000u) ? ~u : (u | 0x80000000u);
  unsigned long long key = ((unsigned long long)u << 32) | (unsigned)bi;
  atomicMin(&packed[row0 + wm*64 + (s >> 2)*16 + lg*4 + (s & 3)], key);
}

// ------------------------------------------- counting-sort segment-sum ----
__global__ __launch_bounds__(256) void count_kernel(
    const unsigned long long* __restrict__ packed, int* __restrict__ cnt,
    float* __restrict__ idxout) {
  int row = blockIdx.x * 256 + threadIdx.x;
  int idx = (int)(packed[row] & 0xFFFFFFFFull);
  idxout[row] = (float)idx;
  atomicAdd(&cnt[idx], 1);
}

__global__ __launch_bounds__(256) void scan_kernel(const int* __restrict__ cnt,
                                                   int* __restrict__ offs,
                                                   int* __restrict__ cursor) {
  int t = threadIdx.x;
  int base = t * 32;
  int local[32];
  int s = 0;
  #pragma unroll
  for (int i = 0; i < 32; i++) { local[i] = s; s += cnt[base + i]; }
  __shared__ int ps[257];
  ps[t + 1] = s;
  if (t == 0) ps[0] = 0;
  __syncthreads();
  if (t == 0) { for (int i = 1; i <= 256; i++) ps[i] += ps[i - 1]; }
  __syncthreads();
  int e = ps[t];
  #pragma unroll
  for (int i = 0; i < 32; i++) {
    int o = e + local[i];
    offs[base + i] = o; cursor[base + i] = o;
  }
  if (t == 255) offs[8192] = ps[256];
}

__global__ __launch_bounds__(256) void scatter_ids(
    const unsigned long long* __restrict__ packed, int* __restrict__ cursor,
    int* __restrict__ rowlist) {
  int row = blockIdx.x * 256 + threadIdx.x;
  int idx = (int)(packed[row] & 0xFFFFFFFFull);
  int pos = atomicAdd(&cursor[idx], 1);
  rowlist[pos] = row;
}

__global__ __launch_bounds__(256) void seg_accum(
    const float* __restrict__ z, const float* __restrict__ edw,
    const float* __restrict__ ecs, const int* __restrict__ offs,
    const int* __restrict__ rowlist, float* __restrict__ nedw_out,
    float* __restrict__ ncs_out) {
  int k = blockIdx.x, t = threadIdx.x;
  int s0 = offs[k], s1 = offs[k + 1];
  float ax = 0.f, ay = 0.f;
  for (int r = s0; r < s1; r++) {
    int row = rowlist[r];
    float2 zv = *(const float2*)&z[(size_t)row * D_N + t * 2];
    ax += zv.x; ay += zv.y;
  }
  float2 ev = *(const float2*)&edw[(size_t)k * D_N + t * 2];
  float2 o;
  o.x = EMA * ev.x + ONE_M_EMA * ax;
  o.y = EMA * ev.y + ONE_M_EMA * ay;
  *(float2*)&nedw_out[(size_t)k * D_N + t * 2] = o;
  if (t == 0) ncs_out[k] = EMA * ecs[k] + ONE_M_EMA * (float)(s1 - s0);
}

// ------------------------------------------------ quantize + loss partial --
__global__ __launch_bounds__(256) void quant_loss(
    const float* __restrict__ z, const float* __restrict__ w,
    const unsigned long long* __restrict__ packed,
    float* __restrict__ qout, float* __restrict__ lpart) {
  int row = blockIdx.x, t = threadIdx.x;
  int idx = (int)(packed[row] & 0xFFFFFFFFull);
  float2 zv = *(const float2*)&z[(size_t)row * D_N + t * 2];
  float2 wv = *(const float2*)&w[(size_t)idx * D_N + t * 2];
  float2 q;
  q.x = zv.x + (wv.x - zv.x);
  q.y = zv.y + (wv.y - zv.y);
  *(float2*)&qout[(size_t)row * D_N + t * 2] = q;
  float dx = zv.x - wv.x, dy = zv.y - wv.y;
  float s = dx * dx + dy * dy;
  #pragma unroll
  for (int off = 32; off; off >>= 1) s += __shfl_down(s, off);
  __shared__ float part[4];
  if ((t & 63) == 0) part[t >> 6] = s;
  __syncthreads();
  if (t == 0) lpart[row] = part[0] + part[1] + part[2] + part[3];
}

// ------------------------------------------------------------- reductions -
__global__ __launch_bounds__(256) void reduce2(const float* __restrict__ ncs_out,
                                               const float* __restrict__ lpart,
                                               float* __restrict__ nsum,
                                               float* __restrict__ loss_sum) {
  int t = threadIdx.x;
  float s1 = 0.f, s2 = 0.f;
  for (int i = t; i < K_N; i += 256) s1 += ncs_out[i];
  for (int i = t; i < B_N; i += 256) s2 += lpart[i];
  #pragma unroll
  for (int off = 32; off; off >>= 1) {
    s1 += __shfl_down(s1, off);
    s2 += __shfl_down(s2, off);
  }
  __shared__ float p1[4], p2[4];
  if ((t & 63) == 0) { p1[t >> 6] = s1; p2[t >> 6] = s2; }
  __syncthreads();
  if (t == 0) {
    nsum[0]     = p1[0] + p1[1] + p1[2] + p1[3];
    loss_sum[0] = p2[0] + p2[1] + p2[2] + p2[3];
  }
}

// fallback-path kernels
__global__ __launch_bounds__(256) void gather_scatter(
    const float* __restrict__ z, const float* __restrict__ w,
    const unsigned long long* __restrict__ packed,
    float* __restrict__ qout, float* __restrict__ idxout,
    float* __restrict__ ncs_out, float* __restrict__ nedw_out,
    float* __restrict__ loss_sum) {
  int row = blockIdx.x;
  int t   = threadIdx.x;
  int idx = (int)(packed[row] & 0xFFFFFFFFull);
  float2 zv = *(const float2*)&z[(size_t)row * D_N + t * 2];
  float2 wv = *(const float2*)&w[(size_t)idx * D_N + t * 2];
  float2 q;
  q.x = zv.x + (wv.x - zv.x);
  q.y = zv.y + (wv.y - zv.y);
  *(float2*)&qout[(size_t)row * D_N + t * 2] = q;
  float dx = zv.x - wv.x, dy = zv.y - wv.y;
  float s = dx*dx + dy*dy;
  #pragma unroll
  for (int off = 32; off; off >>= 1) s += __shfl_down(s, off);
  __shared__ float part[4];
  if ((t & 63) == 0) part[t >> 6] = s;
  __syncthreads();
  if (t == 0) {
    atomicAdd(loss_sum, part[0] + part[1] + part[2] + part[3]);
    atomicAdd(&ncs_out[idx], ONE_M_EMA);
    idxout[row] = (float)idx;
  }
  atomicAdd(&nedw_out[(size_t)idx * D_N + t*2],     ONE_M_EMA * zv.x);
  atomicAdd(&nedw_out[(size_t)idx * D_N + t*2 + 1], ONE_M_EMA * zv.y);
}

__global__ __launch_bounds__(256) void reduce_n(const float* __restrict__ ncs_out,
                                                float* __restrict__ nsum) {
  int t = threadIdx.x;
  float s = 0.f;
  for (int i = t; i < K_N; i += 256) s += ncs_out[i];
  #pragma unroll
  for (int off = 32; off; off >>= 1) s += __shfl_down(s, off);
  __shared__ float part[4];
  if ((t & 63) == 0) part[t >> 6] = s;
  __syncthreads();
  if (t == 0) nsum[0] = part[0] + part[1] + part[2] + part[3];
}

__global__ __launch_bounds__(256) void finalize(
    const float* __restrict__ ncs_out, const float* __restrict__ nedw_out,
    float* __restrict__ nw_out, const float* __restrict__ nsum,
    const float* __restrict__ loss_sum, float* __restrict__ loss_out) {
  size_t i = (size_t)blockIdx.x * 256 + threadIdx.x;
  float n = nsum[0];
  int k = (int)(i >> 9);
  float nv = ncs_out[k];
  float cs = (nv + EPS_) / (n + K_N * EPS_) * n;
  nw_out[i] = nedw_out[i] / cs;
  if (i == 0) loss_out[0] = CCOST * loss_sum[0] / (float)((size_t)B_N * D_N);
}

// ------------------------------------------------------------------ launch -
extern "C" void kernel_launch(void* const* d_in, const int* in_sizes, int n_in,
                              void* d_out, int out_size, void* d_ws, size_t ws_size,
                              hipStream_t stream) {
  const float* z   = (const float*)d_in[0];
  const float* w   = (const float*)d_in[1];
  const float* ecs = (const float*)d_in[2];
  const float* edw = (const float*)d_in[3];

  float* out      = (float*)d_out;
  float* qout     = out;
  float* idxout   = out + (size_t)B_N * D_N;
  float* loss_out = idxout + B_N;
  float* nw_out   = loss_out + 1;
  float* ncs_out  = nw_out + (size_t)K_N * D_N;
  float* nedw_out = ncs_out + K_N;

  unsigned long long* packed = (unsigned long long*)d_ws;
  float* wsq      = (float*)((char*)d_ws + 262144);
  float* loss_sum = (float*)((char*)d_ws + 294912);
  float* nsum     = loss_sum + 1;

  hipMemsetAsync(d_ws, 0xFF, 262144, stream);
  hipMemsetAsync((void*)loss_sum, 0, 8, stream);

  if (ws_size >= WS_NEED) {
    ushort* zp  = (ushort*)((char*)d_ws + ZP_OFF);
    ushort* wp  = (ushort*)((char*)d_ws + WP_OFF);
    int* cnt    = (int*)((char*)d_ws + CNT_OFF);
    int* offs   = (int*)((char*)d_ws + OFFS_OFF);
    int* cursor = (int*)((char*)d_ws + CURS_OFF);
    int* rowl   = (int*)((char*)d_ws + ROWL_OFF);
    float* lpart= (float*)((char*)d_ws + LPART_OFF);

    split_z<<<8192, 256, 0, stream>>>(z, zp);
    split_w<<<2048, 256, 0, stream>>>(w, wp, wsq);   // wsq fused here
    score3p<<<dim3(128, 4), 512, 0, stream>>>(zp, wp, wsq, packed);
    // aux arrays alias zp (dead after score3p) -> init only now
    hipMemsetAsync((void*)cnt, 0, K_N * sizeof(int), stream);
    count_kernel<<<B_N / 256, 256, 0, stream>>>(packed, cnt, idxout);
    scan_kernel<<<1, 256, 0, stream>>>(cnt, offs, cursor);
    scatter_ids<<<B_N / 256, 256, 0, stream>>>(packed, cursor, rowl);
    seg_accum<<<K_N, 256, 0, stream>>>(z, edw, ecs, offs, rowl, nedw_out, ncs_out);
    quant_loss<<<B_N, 256, 0, stream>>>(z, w, packed, qout, lpart);
    reduce2<<<1, 256, 0, stream>>>(ncs_out, lpart, nsum, loss_sum);
  } else {
    prep_kernel<<<2048, 256, 0, stream>>>(w, ecs, wsq, ncs_out);
    prep_nedw<<<4096, 256, 0, stream>>>((const float4*)edw, (float4*)nedw_out);
    score_argmin_mfma<<<dim3(B_N / 128, KSPLIT), 256, 0, stream>>>(z, w, wsq, packed);
    gather_scatter<<<B_N, 256, 0, stream>>>(z, w, packed, qout, idxout,
                                            ncs_out, nedw_out, loss_sum);
    reduce_n<<<1, 256, 0, stream>>>(ncs_out, nsum);
  }

  finalize<<<K_N * D_N / 256, 256, 0, stream>>>(ncs_out, nedw_out, nw_out,
                                                nsum, loss_sum, loss_out);
}

// Round 11
// 1016.680 us; speedup vs baseline: 2.0464x; 1.0064x over previous
//
#include <hip/hip_runtime.h>

#define B_N 32768
#define D_N 512
#define K_N 8192
#define EMA 0.99f
#define ONE_M_EMA 0.01f
#define EPS_ 1e-5f
#define CCOST 0.25f

// ws layout (fast path):
// [0, 262144)            : u64 packed[B_N]  (low32 = idx), init 0xFF
// [262144, 294912)       : float wsq[K_N]
// [294912, 294920)       : float loss_sum, n_sum
// [295936, +67108864)    : ushort zp[32][32768][32]  {hi:0-15, lo:16-31}, chunk-XOR swizzled
// [67404800, +16777216)  : ushort wp[32][8192][32]   {hi:0-15, lo:16-31}
// Logical K' = 1536 = 48 slices; z sections [hi|hi|lo], w sections [hi|lo|hi]
// realized by slice->physical mapping at stage time.
#define ZP_OFF 295936ull
#define WP_OFF 67404800ull
#define WS_NEED (WP_OFF + 16777216ull)
#define CNT_OFF    295936ull
#define OFFS_OFF   332800ull
#define CURS_OFF   365568ull
#define ROWL_OFF   398336ull
#define LPART_OFF  529408ull

typedef __attribute__((ext_vector_type(8))) short bf16x8;
typedef __attribute__((ext_vector_type(4))) float f32x4;

// ---------------------------------------------------------------- prep ----
// (fallback path only; fast path gets wsq from split_w)
__global__ __launch_bounds__(256) void prep_kernel(const float* __restrict__ w,
                                                   const float* __restrict__ ecs,
                                                   float* __restrict__ wsq,
                                                   float* __restrict__ ncs_out) {
  int row  = blockIdx.x * 4 + (threadIdx.x >> 6);
  int lane = threadIdx.x & 63;
  const float* p = w + (size_t)row * D_N + lane * 8;
  float4 a = *(const float4*)p;
  float4 b = *(const float4*)(p + 4);
  float s = a.x*a.x + a.y*a.y + a.z*a.z + a.w*a.w
          + b.x*b.x + b.y*b.y + b.z*b.z + b.w*b.w;
  #pragma unroll
  for (int off = 32; off; off >>= 1) s += __shfl_down(s, off);
  if (lane == 0) wsq[row] = s;

  int gid = blockIdx.x * 256 + threadIdx.x;
  if (gid < K_N) ncs_out[gid] = EMA * ecs[gid];
}

__global__ __launch_bounds__(256) void prep_nedw(const float4* __restrict__ edw,
                                                 float4* __restrict__ nedw) {
  int i = blockIdx.x * 256 + threadIdx.x;
  float4 v = edw[i];
  v.x *= EMA; v.y *= EMA; v.z *= EMA; v.w *= EMA;
  nedw[i] = v;
}

// ------------------------------------------------------------ pre-split ---
// x[R][512] f32 -> xp[32][R][32] bf16: physical sec0 = hi slices, sec1 = lo.
// 16B chunk stored at (c ^ ((row>>1)&3)) -- ds_read-side XOR swizzle baked in.
__global__ __launch_bounds__(256) void split_z(const float* __restrict__ x,
                                               ushort* __restrict__ xp) {
  int g   = blockIdx.x * 256 + threadIdx.x;
  int row = g >> 6, c = g & 63;
  const float* src = x + (size_t)row * 512 + c * 8;
  float v[8];
  *(float4*)&v[0] = *(const float4*)&src[0];
  *(float4*)&v[4] = *(const float4*)&src[4];
  uint hw[4], lw[4];
  #pragma unroll
  for (int i = 0; i < 4; i++) {
    uint b0 = __float_as_uint(v[2*i]);
    uint b1 = __float_as_uint(v[2*i+1]);
    float r0 = v[2*i]   - __uint_as_float(b0 & 0xFFFF0000u);
    float r1 = v[2*i+1] - __uint_as_float(b1 & 0xFFFF0000u);
    hw[i] = (b0 >> 16) | (b1 & 0xFFFF0000u);
    lw[i] = (__float_as_uint(r0) >> 16) | (__float_as_uint(r1) & 0xFFFF0000u);
  }
  int si  = c >> 2;
  int p   = (c & 3) ^ ((row >> 1) & 3);
  size_t sstr = (size_t)B_N * 32;
  size_t base = (size_t)row * 32 + (size_t)p * 8;
  *(uint4*)&xp[(size_t)si * sstr + base]        = (uint4){hw[0], hw[1], hw[2], hw[3]};
  *(uint4*)&xp[(size_t)(16 + si) * sstr + base] = (uint4){lw[0], lw[1], lw[2], lw[3]};
}

// split_w also computes wsq (fused w pass; one wave per row)
__global__ __launch_bounds__(256) void split_w(const float* __restrict__ x,
                                               ushort* __restrict__ xp,
                                               float* __restrict__ wsq) {
  int g   = blockIdx.x * 256 + threadIdx.x;
  int row = g >> 6, c = g & 63;
  const float* src = x + (size_t)row * 512 + c * 8;
  float v[8];
  *(float4*)&v[0] = *(const float4*)&src[0];
  *(float4*)&v[4] = *(const float4*)&src[4];
  uint hw[4], lw[4]; float w2 = 0.f;
  #pragma unroll
  for (int i = 0; i < 4; i++) {
    uint b0 = __float_as_uint(v[2*i]);
    uint b1 = __float_as_uint(v[2*i+1]);
    float r0 = v[2*i]   - __uint_as_float(b0 & 0xFFFF0000u);
    float r1 = v[2*i+1] - __uint_as_float(b1 & 0xFFFF0000u);
    hw[i] = (b0 >> 16) | (b1 & 0xFFFF0000u);
    lw[i] = (__float_as_uint(r0) >> 16) | (__float_as_uint(r1) & 0xFFFF0000u);
    w2 += v[2*i]*v[2*i] + v[2*i+1]*v[2*i+1];
  }
  int si  = c >> 2;
  int p   = (c & 3) ^ ((row >> 1) & 3);
  size_t sstr = (size_t)K_N * 32;
  size_t base = (size_t)row * 32 + (size_t)p * 8;
  *(uint4*)&xp[(size_t)si * sstr + base]        = (uint4){hw[0], hw[1], hw[2], hw[3]};
  *(uint4*)&xp[(size_t)(16 + si) * sstr + base] = (uint4){lw[0], lw[1], lw[2], lw[3]};
  #pragma unroll
  for (int off = 32; off; off >>= 1) w2 += __shfl_down(w2, off);
  if (c == 0) wsq[row] = w2;
}

// --------------------------------------------------------- score+argmin ---
// 256x256 tile, 8 waves (2M x 4N, 128x64 each), BK=32 ring of 4 LDS slots.
// TWO slices per phase (barriers halved vs r6): compute (2P,2P+1) from E/O
// regs; reload E after its last MFMA read (WAR via register deps); stage
// slices (2P+4,2P+5) into slots (2P)&3,(2P+1)&3 (frag-readers drained at the
// previous barrier); one lgkm(0)+vmcnt(0)+barrier per phase (GLDS issue->wait
// spans the whole ~4000cy phase >> HBM latency).
constexpr int COLT2 = 8;

#define GLDS(SRC, DST) __builtin_amdgcn_global_load_lds((const unsigned int*)(SRC), (unsigned int*)(DST), 16, 0, 0)

// stage one logical slice S (0..47 within col-tile ctf) into slot SL
#define STAGE1(S, SL)                                                          \
  {                                                                            \
    const int s__ = (S);                                                       \
    const int zsl_ = (s__ < 32) ? (s__ & 15) : (s__ - 16);  /* [hi|hi|lo] */   \
    const int wsl_ = (s__ < 32) ? s__ : (s__ - 32);         /* [hi|lo|hi] */   \
    GLDS(zA + (size_t)zsl_ * 2097152,        (char*)As[SL] + t * 16);          \
    GLDS(zA + (size_t)zsl_ * 2097152 + 8192, (char*)As[SL] + 8192 + t * 16);   \
    const size_t wOfs_ = (size_t)wsl_ * 524288 + (size_t)ctf * 16384;          \
    GLDS(wB + wOfs_,        (char*)Bs[SL] + t * 16);                           \
    GLDS(wB + wOfs_ + 8192, (char*)Bs[SL] + 8192 + t * 16);                    \
  }

#define LOADFRAG(AX, BX, G)                                                    \
  {                                                                            \
    const char* Ab_ = (const char*)As[(G) & 3] + aoff;                         \
    const char* Bb_ = (const char*)Bs[(G) & 3] + boff;                         \
    _Pragma("unroll")                                                          \
    for (int i_ = 0; i_ < 8; i_++) AX[i_] = *(const bf16x8*)(Ab_ + i_ * 1024); \
    _Pragma("unroll")                                                          \
    for (int j_ = 0; j_ < 4; j_++) BX[j_] = *(const bf16x8*)(Bb_ + j_ * 1024); \
  }

#define MFMABLK(AX, BX)                                                        \
  {                                                                            \
    __builtin_amdgcn_s_setprio(1);                                             \
    _Pragma("unroll")                                                          \
    for (int i_ = 0; i_ < 8; i_++)                                             \
      _Pragma("unroll")                                                        \
      for (int j_ = 0; j_ < 4; j_++)                                           \
        acc[i_][j_] = __builtin_amdgcn_mfma_f32_16x16x32_bf16(AX[i_], BX[j_],  \
                                                        acc[i_][j_], 0, 0, 0); \
    __builtin_amdgcn_s_setprio(0);                                             \
  }

// phase over slices (G2, G2+1); G2 even, global in [0,384)
#define PHASE2(G2)                                                             \
  {                                                                            \
    const int g2_ = (G2);                                                      \
    if (g2_ + 4 <= 383) {          /* stage slices g2+4, g2+5 */               \
      STAGE1(sf,     sf & 3)                                                   \
      STAGE1(sf + 1, (sf + 1) & 3)                                             \
      sf += 2; if (sf == 48) { sf = 0; ctf++; }                                \
    }                                                                          \
    MFMABLK(aE, bE)                /* slice g2 */                              \
    if (g2_ + 2 <= 383) LOADFRAG(aE, bE, g2_ + 2)  /* WAR: after E's reads */  \
    MFMABLK(aO, bO)                /* slice g2+1 */                            \
    if (g2_ + 3 <= 383) LOADFRAG(aO, bO, g2_ + 3)                              \
    asm volatile("s_waitcnt lgkmcnt(0)" ::: "memory");                         \
    asm volatile("s_waitcnt vmcnt(0)" ::: "memory");                           \
    __builtin_amdgcn_s_barrier();                                              \
    __builtin_amdgcn_sched_barrier(0);                                         \
  }

__global__ __launch_bounds__(512, 2) void score3r(
    const ushort* __restrict__ zp, const ushort* __restrict__ wp,
    const float* __restrict__ wsq, unsigned long long* __restrict__ packed) {
  __shared__ ushort As[4][8192];             // 4 slots x [256 rows][32 sh]
  __shared__ ushort Bs[4][8192];
  __shared__ float wsqs[2048];
  __shared__ unsigned long long best2[256][4];

  const int t = threadIdx.x, lane = t & 63, wid = t >> 6;
  const int wm = wid >> 2, wn = wid & 3;     // 2M x 4N wave grid
  const int l15 = lane & 15, lg = (lane >> 4) & 3;
  const int row0 = blockIdx.x * 256;
  const int cg0  = blockIdx.y * 2048;

  const char* zA = (const char*)zp + ((size_t)(row0 + (t >> 2)) * 64 + (size_t)(t & 3) * 16);
  const char* wB = (const char*)wp + ((size_t)(cg0  + (t >> 2)) * 64 + (size_t)(t & 3) * 16);

  const int swz  = (l15 >> 1) & 3;
  const int aoff = (wm * 128 + l15) * 64 + ((lg ^ swz) * 16);
  const int boff = (wn * 64  + l15) * 64 + ((lg ^ swz) * 16);

  { float4 v = *(const float4*)&wsq[cg0 + t * 4]; *(float4*)&wsqs[t * 4] = v; }
  if (t < 256) { best2[t][0] = ~0ull; best2[t][1] = ~0ull; best2[t][2] = ~0ull; best2[t][3] = ~0ull; }
  __syncthreads();                            // wsqs/best2 visible, full drain

  int sf = 4, ctf = 0;                        // next logical slice to stage

  // prologue: stage slices 0..3 (slots 0..3; identity mapping since <16)
  #pragma unroll
  for (int s0 = 0; s0 < 4; s0++) {
    GLDS(zA + (size_t)s0 * 2097152,        (char*)As[s0] + t * 16);
    GLDS(zA + (size_t)s0 * 2097152 + 8192, (char*)As[s0] + 8192 + t * 16);
    GLDS(wB + (size_t)s0 * 524288,         (char*)Bs[s0] + t * 16);
    GLDS(wB + (size_t)s0 * 524288 + 8192,  (char*)Bs[s0] + 8192 + t * 16);
  }
  asm volatile("s_waitcnt vmcnt(0)" ::: "memory");    // all 4 slots landed
  __builtin_amdgcn_s_barrier();
  __builtin_amdgcn_sched_barrier(0);

  bf16x8 aE[8], bE[4], aO[8], bO[4];
  LOADFRAG(aE, bE, 0)
  LOADFRAG(aO, bO, 1)
  asm volatile("s_waitcnt lgkmcnt(0)" ::: "memory");  // frags(0),(1) drained
  __builtin_amdgcn_s_barrier();
  __builtin_amdgcn_sched_barrier(0);

  for (int ct = 0; ct < COLT2; ct++) {
    f32x4 acc[8][4];
    #pragma unroll
    for (int i = 0; i < 8; i++)
      #pragma unroll
      for (int j = 0; j < 4; j++) acc[i][j] = (f32x4){0.f, 0.f, 0.f, 0.f};

    for (int p = 0; p < 24; p++) {            // 24 phases x 2 slices = 48
      PHASE2(ct * 48 + 2 * p)
    }

    // ---- epilogue: distances + argmin for this col-tile
    float rv[32]; int rx[32];
    #pragma unroll
    for (int i = 0; i < 8; i++)
      #pragma unroll
      for (int r = 0; r < 4; r++) {
        float bvv = 3.4e38f; int bii = 0;
        #pragma unroll
        for (int j = 0; j < 4; j++) {
          float wq = wsqs[ct * 256 + wn * 64 + j * 16 + l15];
          float dist = wq - 2.0f * acc[i][j][r];
          int c = cg0 + ct * 256 + wn * 64 + j * 16 + l15;
          if (dist < bvv) { bvv = dist; bii = c; }   // j ascending: first idx wins
        }
        rv[i * 4 + r] = bvv; rx[i * 4 + r] = bii;
      }
    #pragma unroll
    for (int e = 0; e < 32; e++) {
      float v = rv[e]; int ix = rx[e];
      #pragma unroll
      for (int m = 1; m < 16; m <<= 1) {
        float ov = __shfl_xor(v, m, 64);
        int   oi = __shfl_xor(ix, m, 64);
        if (ov < v || (ov == v && oi < ix)) { v = ov; ix = oi; }
      }
      rv[e] = v; rx[e] = ix;
    }
    #pragma unroll
    for (int half = 0; half < 2; half++) {     // lane l15 commits entries l15, l15+16
      const int e0 = l15 + half * 16;
      float bvv = 0.f; int bii = 0;
      #pragma unroll
      for (int e = 0; e < 32; e++) {            // static-index select (rule #20)
        bool p2 = (e == e0);
        bvv = p2 ? rv[e] : bvv; bii = p2 ? rx[e] : bii;
      }
      unsigned u = __float_as_uint(bvv);
      u = (u & 0x80000000u) ? ~u : (u | 0x80000000u);
      unsigned long long key = ((unsigned long long)u << 32) | (unsigned)bii;
      const int rowl = wm * 128 + (e0 >> 2) * 16 + lg * 4 + (e0 & 3);
      unsigned long long cur = best2[rowl][wn];  // single-writer slot: no atomic
      if (key < cur) best2[rowl][wn] = key;
    }
  }

  __syncthreads();
  if (t < 256) {
    unsigned long long k0 = best2[t][0], k1 = best2[t][1];
    unsigned long long k2 = best2[t][2], k3 = best2[t][3];
    unsigned long long m0 = k0 < k1 ? k0 : k1;
    unsigned long long m1 = k2 < k3 ? k2 : k3;
    atomicMin(&packed[row0 + t], m0 < m1 ? m0 : m1);
  }
}

// ---------------------------------------- fallback score (round-2 kernel) --
constexpr int LDP = 40;
constexpr int KSPLIT = 8, COLT = K_N / KSPLIT / 128;
__device__ __forceinline__ void stage16(const float* __restrict__ g,
                                        ushort* __restrict__ h,
                                        ushort* __restrict__ l) {
  float v[16];
  *(float4*)&v[0]  = *(const float4*)&g[0];
  *(float4*)&v[4]  = *(const float4*)&g[4];
  *(float4*)&v[8]  = *(const float4*)&g[8];
  *(float4*)&v[12] = *(const float4*)&g[12];
  uint hw[8], lw[8];
  #pragma unroll
  for (int i = 0; i < 8; i++) {
    uint b0 = __float_as_uint(v[2*i]);
    uint b1 = __float_as_uint(v[2*i+1]);
    float r0 = v[2*i]   - __uint_as_float(b0 & 0xFFFF0000u);
    float r1 = v[2*i+1] - __uint_as_float(b1 & 0xFFFF0000u);
    hw[i] = (b0 >> 16) | (b1 & 0xFFFF0000u);
    lw[i] = (__float_as_uint(r0) >> 16) | (__float_as_uint(r1) & 0xFFFF0000u);
  }
  ((uint4*)h)[0] = *(uint4*)&hw[0];
  ((uint4*)h)[1] = *(uint4*)&hw[4];
  ((uint4*)l)[0] = *(uint4*)&lw[0];
  ((uint4*)l)[1] = *(uint4*)&lw[4];
}

__global__ __launch_bounds__(256, 2) void score_argmin_mfma(
    const float* __restrict__ z, const float* __restrict__ w,
    const float* __restrict__ wsq, unsigned long long* __restrict__ packed) {
  __shared__ ushort Ah[128][LDP];
  __shared__ ushort Al[128][LDP];
  __shared__ ushort Bh[128][LDP];
  __shared__ ushort Bl[128][LDP];
  const int t = threadIdx.x, lane = t & 63, wid = t >> 6;
  const int wm = wid >> 1, wn = wid & 1;
  const int l15 = lane & 15, lg = lane >> 4;
  const int row0 = blockIdx.x * 128;
  const int ks0  = blockIdx.y * (K_N / KSPLIT);
  const int srow = t >> 1, skq = (t & 1) * 16;
  float rmin[16]; int ridx[16];
  #pragma unroll
  for (int e = 0; e < 16; e++) { rmin[e] = 3.4e38f; ridx[e] = 0; }
  for (int ct = 0; ct < COLT; ct++) {
    const int c0 = ks0 + ct * 128;
    f32x4 acc[4][4];
    #pragma unroll
    for (int i = 0; i < 4; i++)
      #pragma unroll
      for (int j = 0; j < 4; j++) acc[i][j] = (f32x4){0.f, 0.f, 0.f, 0.f};
    for (int k0 = 0; k0 < D_N; k0 += 32) {
      __syncthreads();
      stage16(&z[(size_t)(row0 + srow) * D_N + k0 + skq], &Ah[srow][skq], &Al[srow][skq]);
      stage16(&w[(size_t)(c0   + srow) * D_N + k0 + skq], &Bh[srow][skq], &Bl[srow][skq]);
      __syncthreads();
      bf16x8 ah[4], al[4], bh[4], bl[4];
      #pragma unroll
      for (int i = 0; i < 4; i++) {
        ah[i] = *(const bf16x8*)&Ah[wm*64 + i*16 + l15][lg*8];
        al[i] = *(const bf16x8*)&Al[wm*64 + i*16 + l15][lg*8];
        bh[i] = *(const bf16x8*)&Bh[wn*64 + i*16 + l15][lg*8];
        bl[i] = *(const bf16x8*)&Bl[wn*64 + i*16 + l15][lg*8];
      }
      #pragma unroll
      for (int i = 0; i < 4; i++)
        #pragma unroll
        for (int j = 0; j < 4; j++) {
          acc[i][j] = __builtin_amdgcn_mfma_f32_16x16x32_bf16(ah[i], bh[j], acc[i][j], 0, 0, 0);
          acc[i][j] = __builtin_amdgcn_mfma_f32_16x16x32_bf16(ah[i], bl[j], acc[i][j], 0, 0, 0);
          acc[i][j] = __builtin_amdgcn_mfma_f32_16x16x32_bf16(al[i], bh[j], acc[i][j], 0, 0, 0);
        }
    }
    float wq[4];
    #pragma unroll
    for (int j = 0; j < 4; j++) wq[j] = wsq[c0 + wn*64 + j*16 + l15];
    #pragma unroll
    for (int i = 0; i < 4; i++)
      #pragma unroll
      for (int r = 0; r < 4; r++) {
        const int e = i * 4 + r;
        #pragma unroll
        for (int j = 0; j < 4; j++) {
          float dist = wq[j] - 2.0f * acc[i][j][r];
          if (dist < rmin[e]) { rmin[e] = dist; ridx[e] = c0 + wn*64 + j*16 + l15; }
        }
      }
  }
  #pragma unroll
  for (int e = 0; e < 16; e++) {
    float v = rmin[e]; int ix = ridx[e];
    #pragma unroll
    for (int m = 1; m < 16; m <<= 1) {
      float ov = __shfl_xor(v, m, 64);
      int   oi = __shfl_xor(ix, m, 64);
      if (ov < v || (ov == v && oi < ix)) { v = ov; ix = oi; }
    }
    rmin[e] = v; ridx[e] = ix;
  }
  const int s = l15;
  float bv = 0.f; int bi = 0;
  #pragma unroll
  for (int e = 0; e < 16; e++) {
    bool p = (e == s);
    bv = p ? rmin[e] : bv;
    bi = p ? ridx[e] : bi;
  }
  unsigned u = __float_as_uint(bv);
  u = (u & 0x80000000u) ? ~u : (u | 0x80000000u);
  unsigned long long key = ((unsigned long long)u << 32) | (unsigned)bi;
  atomicMin(&packed[row0 + wm*64 + (s >> 2)*16 + lg*4 + (s & 3)], key);
}

// ------------------------------------------- counting-sort segment-sum ----
__global__ __launch_bounds__(256) void count_kernel(
    const unsigned long long* __restrict__ packed, int* __restrict__ cnt,
    float* __restrict__ idxout) {
  int row = blockIdx.x * 256 + threadIdx.x;
  int idx = (int)(packed[row] & 0xFFFFFFFFull);
  idxout[row] = (float)idx;
  atomicAdd(&cnt[idx], 1);
}

__global__ __launch_bounds__(256) void scan_kernel(const int* __restrict__ cnt,
                                                   int* __restrict__ offs,
                                                   int* __restrict__ cursor) {
  int t = threadIdx.x;
  int base = t * 32;
  int local[32];
  int s = 0;
  #pragma unroll
  for (int i = 0; i < 32; i++) { local[i] = s; s += cnt[base + i]; }
  __shared__ int ps[257];
  ps[t + 1] = s;
  if (t == 0) ps[0] = 0;
  __syncthreads();
  if (t == 0) { for (int i = 1; i <= 256; i++) ps[i] += ps[i - 1]; }
  __syncthreads();
  int e = ps[t];
  #pragma unroll
  for (int i = 0; i < 32; i++) {
    int o = e + local[i];
    offs[base + i] = o; cursor[base + i] = o;
  }
  if (t == 255) offs[8192] = ps[256];
}

__global__ __launch_bounds__(256) void scatter_ids(
    const unsigned long long* __restrict__ packed, int* __restrict__ cursor,
    int* __restrict__ rowlist) {
  int row = blockIdx.x * 256 + threadIdx.x;
  int idx = (int)(packed[row] & 0xFFFFFFFFull);
  int pos = atomicAdd(&cursor[idx], 1);
  rowlist[pos] = row;
}

__global__ __launch_bounds__(256) void seg_accum(
    const float* __restrict__ z, const float* __restrict__ edw,
    const float* __restrict__ ecs, const int* __restrict__ offs,
    const int* __restrict__ rowlist, float* __restrict__ nedw_out,
    float* __restrict__ ncs_out) {
  int k = blockIdx.x, t = threadIdx.x;
  int s0 = offs[k], s1 = offs[k + 1];
  float ax = 0.f, ay = 0.f;
  for (int r = s0; r < s1; r++) {
    int row = rowlist[r];
    float2 zv = *(const float2*)&z[(size_t)row * D_N + t * 2];
    ax += zv.x; ay += zv.y;
  }
  float2 ev = *(const float2*)&edw[(size_t)k * D_N + t * 2];
  float2 o;
  o.x = EMA * ev.x + ONE_M_EMA * ax;
  o.y = EMA * ev.y + ONE_M_EMA * ay;
  *(float2*)&nedw_out[(size_t)k * D_N + t * 2] = o;
  if (t == 0) ncs_out[k] = EMA * ecs[k] + ONE_M_EMA * (float)(s1 - s0);
}

// ------------------------------------------------ quantize + loss partial --
__global__ __launch_bounds__(256) void quant_loss(
    const float* __restrict__ z, const float* __restrict__ w,
    const unsigned long long* __restrict__ packed,
    float* __restrict__ qout, float* __restrict__ lpart) {
  int row = blockIdx.x, t = threadIdx.x;
  int idx = (int)(packed[row] & 0xFFFFFFFFull);
  float2 zv = *(const float2*)&z[(size_t)row * D_N + t * 2];
  float2 wv = *(const float2*)&w[(size_t)idx * D_N + t * 2];
  float2 q;
  q.x = zv.x + (wv.x - zv.x);
  q.y = zv.y + (wv.y - zv.y);
  *(float2*)&qout[(size_t)row * D_N + t * 2] = q;
  float dx = zv.x - wv.x, dy = zv.y - wv.y;
  float s = dx * dx + dy * dy;
  #pragma unroll
  for (int off = 32; off; off >>= 1) s += __shfl_down(s, off);
  __shared__ float part[4];
  if ((t & 63) == 0) part[t >> 6] = s;
  __syncthreads();
  if (t == 0) lpart[row] = part[0] + part[1] + part[2] + part[3];
}

// ------------------------------------------------------------- reductions -
__global__ __launch_bounds__(256) void reduce2(const float* __restrict__ ncs_out,
                                               const float* __restrict__ lpart,
                                               float* __restrict__ nsum,
                                               float* __restrict__ loss_sum) {
  int t = threadIdx.x;
  float s1 = 0.f, s2 = 0.f;
  for (int i = t; i < K_N; i += 256) s1 += ncs_out[i];
  for (int i = t; i < B_N; i += 256) s2 += lpart[i];
  #pragma unroll
  for (int off = 32; off; off >>= 1) {
    s1 += __shfl_down(s1, off);
    s2 += __shfl_down(s2, off);
  }
  __shared__ float p1[4], p2[4];
  if ((t & 63) == 0) { p1[t >> 6] = s1; p2[t >> 6] = s2; }
  __syncthreads();
  if (t == 0) {
    nsum[0]     = p1[0] + p1[1] + p1[2] + p1[3];
    loss_sum[0] = p2[0] + p2[1] + p2[2] + p2[3];
  }
}

// fallback-path kernels
__global__ __launch_bounds__(256) void gather_scatter(
    const float* __restrict__ z, const float* __restrict__ w,
    const unsigned long long* __restrict__ packed,
    float* __restrict__ qout, float* __restrict__ idxout,
    float* __restrict__ ncs_out, float* __restrict__ nedw_out,
    float* __restrict__ loss_sum) {
  int row = blockIdx.x;
  int t   = threadIdx.x;
  int idx = (int)(packed[row] & 0xFFFFFFFFull);
  float2 zv = *(const float2*)&z[(size_t)row * D_N + t * 2];
  float2 wv = *(const float2*)&w[(size_t)idx * D_N + t * 2];
  float2 q;
  q.x = zv.x + (wv.x - zv.x);
  q.y = zv.y + (wv.y - zv.y);
  *(float2*)&qout[(size_t)row * D_N + t * 2] = q;
  float dx = zv.x - wv.x, dy = zv.y - wv.y;
  float s = dx*dx + dy*dy;
  #pragma unroll
  for (int off = 32; off; off >>= 1) s += __shfl_down(s, off);
  __shared__ float part[4];
  if ((t & 63) == 0) part[t >> 6] = s;
  __syncthreads();
  if (t == 0) {
    atomicAdd(loss_sum, part[0] + part[1] + part[2] + part[3]);
    atomicAdd(&ncs_out[idx], ONE_M_EMA);
    idxout[row] = (float)idx;
  }
  atomicAdd(&nedw_out[(size_t)idx * D_N + t*2],     ONE_M_EMA * zv.x);
  atomicAdd(&nedw_out[(size_t)idx * D_N + t*2 + 1], ONE_M_EMA * zv.y);
}

__global__ __launch_bounds__(256) void reduce_n(const float* __restrict__ ncs_out,
                                                float* __restrict__ nsum) {
  int t = threadIdx.x;
  float s = 0.f;
  for (int i = t; i < K_N; i += 256) s += ncs_out[i];
  #pragma unroll
  for (int off = 32; off; off >>= 1) s += __shfl_down(s, off);
  __shared__ float part[4];
  if ((t & 63) == 0) part[t >> 6] = s;
  __syncthreads();
  if (t == 0) nsum[0] = part[0] + part[1] + part[2] + part[3];
}

__global__ __launch_bounds__(256) void finalize(
    const float* __restrict__ ncs_out, const float* __restrict__ nedw_out,
    float* __restrict__ nw_out, const float* __restrict__ nsum,
    const float* __restrict__ loss_sum, float* __restrict__ loss_out) {
  size_t i = (size_t)blockIdx.x * 256 + threadIdx.x;
  float n = nsum[0];
  int k = (int)(i >> 9);
  float nv = ncs_out[k];
  float cs = (nv + EPS_) / (n + K_N * EPS_) * n;
  nw_out[i] = nedw_out[i] / cs;
  if (i == 0) loss_out[0] = CCOST * loss_sum[0] / (float)((size_t)B_N * D_N);
}

// ------------------------------------------------------------------ launch -
extern "C" void kernel_launch(void* const* d_in, const int* in_sizes, int n_in,
                              void* d_out, int out_size, void* d_ws, size_t ws_size,
                              hipStream_t stream) {
  const float* z   = (const float*)d_in[0];
  const float* w   = (const float*)d_in[1];
  const float* ecs = (const float*)d_in[2];
  const float* edw = (const float*)d_in[3];

  float* out      = (float*)d_out;
  float* qout     = out;
  float* idxout   = out + (size_t)B_N * D_N;
  float* loss_out = idxout + B_N;
  float* nw_out   = loss_out + 1;
  float* ncs_out  = nw_out + (size_t)K_N * D_N;
  float* nedw_out = ncs_out + K_N;

  unsigned long long* packed = (unsigned long long*)d_ws;
  float* wsq      = (float*)((char*)d_ws + 262144);
  float* loss_sum = (float*)((char*)d_ws + 294912);
  float* nsum     = loss_sum + 1;

  hipMemsetAsync(d_ws, 0xFF, 262144, stream);
  hipMemsetAsync((void*)loss_sum, 0, 8, stream);

  if (ws_size >= WS_NEED) {
    ushort* zp  = (ushort*)((char*)d_ws + ZP_OFF);
    ushort* wp  = (ushort*)((char*)d_ws + WP_OFF);
    int* cnt    = (int*)((char*)d_ws + CNT_OFF);
    int* offs   = (int*)((char*)d_ws + OFFS_OFF);
    int* cursor = (int*)((char*)d_ws + CURS_OFF);
    int* rowl   = (int*)((char*)d_ws + ROWL_OFF);
    float* lpart= (float*)((char*)d_ws + LPART_OFF);

    split_z<<<8192, 256, 0, stream>>>(z, zp);
    split_w<<<2048, 256, 0, stream>>>(w, wp, wsq);   // wsq fused here
    score3r<<<dim3(128, 4), 512, 0, stream>>>(zp, wp, wsq, packed);
    // aux arrays alias zp (dead after score3r) -> init only now
    hipMemsetAsync((void*)cnt, 0, K_N * sizeof(int), stream);
    count_kernel<<<B_N / 256, 256, 0, stream>>>(packed, cnt, idxout);
    scan_kernel<<<1, 256, 0, stream>>>(cnt, offs, cursor);
    scatter_ids<<<B_N / 256, 256, 0, stream>>>(packed, cursor, rowl);
    seg_accum<<<K_N, 256, 0, stream>>>(z, edw, ecs, offs, rowl, nedw_out, ncs_out);
    quant_loss<<<B_N, 256, 0, stream>>>(z, w, packed, qout, lpart);
    reduce2<<<1, 256, 0, stream>>>(ncs_out, lpart, nsum, loss_sum);
  } else {
    prep_kernel<<<2048, 256, 0, stream>>>(w, ecs, wsq, ncs_out);
    prep_nedw<<<4096, 256, 0, stream>>>((const float4*)edw, (float4*)nedw_out);
    score_argmin_mfma<<<dim3(B_N / 128, KSPLIT), 256, 0, stream>>>(z, w, wsq, packed);
    gather_scatter<<<B_N, 256, 0, stream>>>(z, w, packed, qout, idxout,
                                            ncs_out, nedw_out, loss_sum);
    reduce_n<<<1, 256, 0, stream>>>(ncs_out, nsum);
  }

  finalize<<<K_N * D_N / 256, 256, 0, stream>>>(ncs_out, nedw_out, nw_out,
                                                nsum, loss_sum, loss_out);
}